// Round 3
// baseline (1072.208 us; speedup 1.0000x reference)
//
#include <hip/hip_runtime.h>
#include <stdint.h>

#define B_  16
#define QL  2048
#define KL  2048
#define FD  128
#define BQ  64
#define BK  32
#define NSTEP (KL/BK)

#define KSTR  136        // K-tile LDS row stride (shorts)
#define VTOFF 4352       // 32*136
#define VTSTR 36         // V^T LDS row stride (shorts); b128 reads conflict-free
#define BUFS  8960       // 4352 + 128*36 shorts per buffer
#define WS_HALF (B_*KL*FD)   // shorts per converted array (8 MB)

typedef __attribute__((ext_vector_type(8))) short bf16x8;
typedef __attribute__((ext_vector_type(4))) float f32x4;
typedef __attribute__((ext_vector_type(4))) int   i32x4;
typedef __attribute__((ext_vector_type(4))) unsigned int u32x4;

__device__ __forceinline__ unsigned short f2b(float f) {
  union { float f; unsigned u; } x; x.f = f;
  return (unsigned short)((x.u + 0x8000u) >> 16);
}

// pack two f32 -> one dword of two bf16 (lo = first arg)
__device__ __forceinline__ unsigned cvt_pk_bf16(float lo, float hi) {
  unsigned r;
  asm("v_cvt_pk_bf16_f32 %0, %1, %2" : "=v"(r) : "v"(lo), "v"(hi));
  return r;
}

// ---- pre-pass 1: K fp32 -> bf16, same layout ----
__global__ __launch_bounds__(256) void conv_k(const float* __restrict__ kp,
                                              unsigned short* __restrict__ kb) {
  int idx = (blockIdx.x * 256 + threadIdx.x) * 4;
  float4 u = *(const float4*)(kp + idx);
  ushort4 s4; s4.x = f2b(u.x); s4.y = f2b(u.y); s4.z = f2b(u.z); s4.w = f2b(u.w);
  *(ushort4*)(kb + idx) = s4;
}

// ---- pre-pass 2: V fp32 [b][k][f] -> bf16 tiled-transposed [b][kt][f][32] ----
__global__ __launch_bounds__(256) void conv_vt(const float* __restrict__ vp,
                                               unsigned short* __restrict__ vt) {
  __shared__ float tl[32 * 132];
  const int t = threadIdx.x, b = blockIdx.x >> 6, kt = blockIdx.x & 63;
  const int r = t >> 3, f0 = (t & 7) * 16;
  const float* src = vp + ((long long)(b * KL + kt * 32 + r)) * FD + f0;
  #pragma unroll
  for (int i = 0; i < 4; ++i)
    *(float4*)&tl[r * 132 + f0 + 4 * i] = *(const float4*)(src + 4 * i);
  __syncthreads();
  const int f = t >> 1, half = t & 1;
  bf16x8 o0, o1;
  #pragma unroll
  for (int j = 0; j < 8; ++j)  o0[j] = (short)f2b(tl[(half * 16 + j) * 132 + f]);
  #pragma unroll
  for (int j = 0; j < 8; ++j)  o1[j] = (short)f2b(tl[(half * 16 + 8 + j) * 132 + f]);
  unsigned short* dst = vt + ((long long)((b * 64 + kt) * FD + f)) * 32 + half * 16;
  *(bf16x8*)dst = o0;
  *(bf16x8*)(dst + 8) = o1;
}

// out = (sum_k !attn*e^s*V)/l - sum_k !attn*!alibi*d*bscale*V,  l = sum_k e^s
//
// R2: split-K across blocks. Grid was 512 = 2 blocks/CU = 2 waves/SIMD, and
// all pipes idle (MfmaUtil 8%, VALU 25%, HBM 15%, LDS ~20%): latency-bound
// with bubbles. SPLIT=1: each block does half the K range (32 tiles), grid
// 1024 = 4 blocks/CU = 4 waves/SIMD (VGPR<=128 forced, LDS 4x35.8=143KB).
// Halves write fp32 partials (O1,O2,lsum); combine kernel finishes.
template<int SPLIT>
__global__ __launch_bounds__(256, 4) void alibi_attn(
    const unsigned short* __restrict__ kbp,   // bf16 K [b][k][f]
    const unsigned short* __restrict__ vtp,   // bf16 V^T tiles [b][kt][f][32]
    const float* __restrict__ qp,
    const float* __restrict__ cqp,
    const float* __restrict__ ckp,
    const int* __restrict__ amp,
    const int* __restrict__ almp,
    const float* __restrict__ bsp,
    const float* __restrict__ rmp,
    float* __restrict__ outp,
    float* __restrict__ o1p,
    float* __restrict__ o2p,
    float* __restrict__ lsp)
{
  __shared__ unsigned short kv[2 * BUFS];            // 35 KB K + V^T dbuf

  const int NT = SPLIT ? (NSTEP / 2) : NSTEP;

  const int t    = threadIdx.x;
  const int w    = t >> 6;
  const int lane = t & 63;
  const int l15  = lane & 15;
  const int q4   = lane >> 4;

  const int bid  = blockIdx.x;
  const int half = SPLIT ? (bid >> 9) : 0;
  const int bid5 = bid & 511;
  const int xcd  = bid5 & 7, slot = bid5 >> 3;
  const int b    = (xcd << 1) | (slot >> 5);
  const int qbase = (slot & 31) * BQ;
  const int kt0  = half * NT;

  const float bscale = bsp[0] / rmp[0];
  const float sl2 = 0.08838834764831845f * 1.44269504089f;  // scale*log2(e)

  const int kr_st = t >> 3, kc_st = (t & 7) * 16;  // K staging
  const int vf_st = t >> 1, vh_st = (t & 1) * 16;  // V staging

  // ---- prologue: Q tile -> LDS buf0 (transient), grab B-frags + coords ----
  {
    const float* qg = qp + ((long long)(b * QL + qbase)) * FD;
    #pragma unroll
    for (int i = 0; i < 8; ++i) {
      int idx = t + 256 * i;
      float4 u = ((const float4*)qg)[idx];
      int row = idx >> 5, col = (idx & 31) * 4;
      ushort4 s4; s4.x = f2b(u.x); s4.y = f2b(u.y); s4.z = f2b(u.z); s4.w = f2b(u.w);
      *(ushort4*)&kv[row * KSTR + col] = s4;
    }
  }
  __syncthreads();
  bf16x8 qfrag[4];
  {
    const int m = w * 16 + l15;
    #pragma unroll
    for (int fs = 0; fs < 4; ++fs)
      qfrag[fs] = *(const bf16x8*)&kv[m * KSTR + fs * 32 + q4 * 8];
  }
  // this lane's q-row (swapped layout: q = l15 within the wave's 16 rows)
  const int qrow = qbase + w * 16 + l15;
  float cqx, cqy;
  {
    float2 c2 = *(const float2*)(cqp + ((long long)(b * QL + qrow)) * 2);
    cqx = c2.x; cqy = c2.y;
  }
  const long long mrow = (long long)(b * QL + qrow) * KL;
  __syncthreads();

  const unsigned short* kgb = kbp + (long long)b * KL * FD;
  const unsigned short* vgb = vtp + (long long)b * KL * FD;

  // ---- masks/coords step 0 (regs), K/V tile kt0 -> LDS buf0, kt0+1 -> regs ----
  i32x4 amv[2][2], alv[2][2];          // [set][s], component r
  f32x4 ckf[2][2][2];                  // [set][s][pair(r>>1)]: (x,y,x,y)
  bf16x8 kreg[2][2], vreg[2][2];
  const int klane0 = 4 * q4;           // lane's k_local base (s adds 16)
  #pragma unroll
  for (int s = 0; s < 2; ++s) {
    const int k0 = kt0 * BK + s * 16 + klane0;
    amv[0][s] = __builtin_nontemporal_load((const i32x4*)(amp + mrow + k0));
    alv[0][s] = __builtin_nontemporal_load((const i32x4*)(almp + mrow + k0));
    ckf[0][s][0] = *(const f32x4*)(ckp + ((long long)(b * KL + k0)) * 2);
    ckf[0][s][1] = *(const f32x4*)(ckp + ((long long)(b * KL + k0)) * 2 + 4);
  }
  {
    bf16x8 k0l = *(const bf16x8*)(kgb + (kt0 * BK + kr_st) * FD + kc_st);
    bf16x8 k1l = *(const bf16x8*)(kgb + (kt0 * BK + kr_st) * FD + kc_st + 8);
    bf16x8 v0l = *(const bf16x8*)(vgb + kt0 * (BK * FD) + t * 16);
    bf16x8 v1l = *(const bf16x8*)(vgb + kt0 * (BK * FD) + t * 16 + 8);
    *(bf16x8*)&kv[kr_st * KSTR + kc_st]     = k0l;
    *(bf16x8*)&kv[kr_st * KSTR + kc_st + 8] = k1l;
    *(bf16x8*)&kv[VTOFF + vf_st * VTSTR + vh_st]     = v0l;
    *(bf16x8*)&kv[VTOFF + vf_st * VTSTR + vh_st + 8] = v1l;
    // tile kt0+1 into register set 1 (drained at bottom of body 0)
    kreg[1][0] = *(const bf16x8*)(kgb + ((kt0 + 1) * BK + kr_st) * FD + kc_st);
    kreg[1][1] = *(const bf16x8*)(kgb + ((kt0 + 1) * BK + kr_st) * FD + kc_st + 8);
    vreg[1][0] = *(const bf16x8*)(vgb + (kt0 + 1) * (BK * FD) + t * 16);
    vreg[1][1] = *(const bf16x8*)(vgb + (kt0 + 1) * (BK * FD) + t * 16 + 8);
  }
  __syncthreads();

  f32x4 O1[8], O2[8];
  #pragma unroll
  for (int n = 0; n < 8; ++n) {
    O1[n] = (f32x4){0.f, 0.f, 0.f, 0.f};
    O2[n] = (f32x4){0.f, 0.f, 0.f, 0.f};
  }
  float lsum = 0.f;

  // cross-lane gather sources for the in-register P/T transpose
  const int srcA = l15 + ((q4 & 1) << 5);
  const int srcB = srcA + 16;
  const bool lowhalf = (q4 < 2);

  #pragma unroll 2
  for (int kt = 0; kt < NT; ++kt) {
    const int cur = kt & 1, nxt = cur ^ 1;
    const unsigned short* kb = kv + cur * BUFS;
    unsigned short*       nb = kv + nxt * BUFS;

    // ---- fill reg set `cur` with tile kt+2 (consumed 2 bodies later) ----
    const int ktf = kt0 + ((kt + 2 < NT) ? (kt + 2) : (NT - 1));
    kreg[cur][0] = *(const bf16x8*)(kgb + (ktf * BK + kr_st) * FD + kc_st);
    kreg[cur][1] = *(const bf16x8*)(kgb + (ktf * BK + kr_st) * FD + kc_st + 8);
    vreg[cur][0] = *(const bf16x8*)(vgb + ktf * (BK * FD) + t * 16);
    vreg[cur][1] = *(const bf16x8*)(vgb + ktf * (BK * FD) + t * 16 + 8);

    // ---- masks + coords for step kt+1 (dist-1, vector loads) ----
    const int ktm = kt0 + ((kt + 1 < NT) ? (kt + 1) : (NT - 1));
    #pragma unroll
    for (int s = 0; s < 2; ++s) {
      const int kg = ktm * BK + s * 16 + klane0;
      amv[nxt][s] = __builtin_nontemporal_load((const i32x4*)(amp + mrow + kg));
      alv[nxt][s] = __builtin_nontemporal_load((const i32x4*)(almp + mrow + kg));
      ckf[nxt][s][0] = *(const f32x4*)(ckp + ((long long)(b * KL + kg)) * 2);
      ckf[nxt][s][1] = *(const f32x4*)(ckp + ((long long)(b * KL + kg)) * 2 + 4);
    }

    // ---- QK^T (SWAPPED: A=K, B=Q) over F=128 from LDS buf cur ----
    // lane holds S[k = s*16 + 4*q4 + r][q = l15]
    f32x4 S0 = (f32x4){0.f, 0.f, 0.f, 0.f};
    f32x4 S1 = (f32x4){0.f, 0.f, 0.f, 0.f};
    #pragma unroll
    for (int fs = 0; fs < 4; ++fs) {
      bf16x8 kb0 = *(const bf16x8*)&kb[(l15)      * KSTR + fs * 32 + q4 * 8];
      bf16x8 kb1 = *(const bf16x8*)&kb[(16 + l15) * KSTR + fs * 32 + q4 * 8];
      S0 = __builtin_amdgcn_mfma_f32_16x16x32_bf16(kb0, qfrag[fs], S0, 0, 0, 0);
      S1 = __builtin_amdgcn_mfma_f32_16x16x32_bf16(kb1, qfrag[fs], S1, 0, 0, 0);
    }

    // ---- transform (all 8 elements belong to q = qrow) ----
    float wvv[2][4], tvv[2][4];
    #pragma unroll
    for (int s = 0; s < 2; ++s) {
      const f32x4 Sv = s ? S1 : S0;
      #pragma unroll
      for (int r = 0; r < 4; ++r) {
        float e = __builtin_amdgcn_exp2f(Sv[r] * sl2);
        lsum += e;
        const float ckx = ckf[cur][s][r >> 1][(r & 1) * 2];
        const float cky = ckf[cur][s][r >> 1][(r & 1) * 2 + 1];
        float dx = cqx - ckx, dy = cqy - cky;
        float d  = sqrtf(fmaf(dx, dx, dy * dy)) * bscale;
        int am = amv[cur][s][r], al = alv[cur][s][r];
        wvv[s][r] = am ? 0.f : e;
        tvv[s][r] = (am | al) ? 0.f : d;
      }
    }

    // ---- pack to bf16 + in-register transpose into PV A-frag layout ----
    unsigned aX0 = cvt_pk_bf16(wvv[0][0], wvv[0][1]);
    unsigned aX1 = cvt_pk_bf16(wvv[0][2], wvv[0][3]);
    unsigned aX2 = cvt_pk_bf16(wvv[1][0], wvv[1][1]);
    unsigned aX3 = cvt_pk_bf16(wvv[1][2], wvv[1][3]);
    unsigned tX0 = cvt_pk_bf16(tvv[0][0], tvv[0][1]);
    unsigned tX1 = cvt_pk_bf16(tvv[0][2], tvv[0][3]);
    unsigned tX2 = cvt_pk_bf16(tvv[1][0], tvv[1][1]);
    unsigned tX3 = cvt_pk_bf16(tvv[1][2], tvv[1][3]);

    u32x4 wa, ta;
    {
      int y0, y2;
      y0 = __shfl((int)aX0, srcA); y2 = __shfl((int)aX2, srcA);
      wa[0] = (unsigned)(lowhalf ? y0 : y2);
      y0 = __shfl((int)aX1, srcA); y2 = __shfl((int)aX3, srcA);
      wa[1] = (unsigned)(lowhalf ? y0 : y2);
      y0 = __shfl((int)aX0, srcB); y2 = __shfl((int)aX2, srcB);
      wa[2] = (unsigned)(lowhalf ? y0 : y2);
      y0 = __shfl((int)aX1, srcB); y2 = __shfl((int)aX3, srcB);
      wa[3] = (unsigned)(lowhalf ? y0 : y2);
      y0 = __shfl((int)tX0, srcA); y2 = __shfl((int)tX2, srcA);
      ta[0] = (unsigned)(lowhalf ? y0 : y2);
      y0 = __shfl((int)tX1, srcA); y2 = __shfl((int)tX3, srcA);
      ta[1] = (unsigned)(lowhalf ? y0 : y2);
      y0 = __shfl((int)tX0, srcB); y2 = __shfl((int)tX2, srcB);
      ta[2] = (unsigned)(lowhalf ? y0 : y2);
      y0 = __shfl((int)tX1, srcB); y2 = __shfl((int)tX3, srcB);
      ta[3] = (unsigned)(lowhalf ? y0 : y2);
    }
    bf16x8 aw = __builtin_bit_cast(bf16x8, wa);
    bf16x8 at = __builtin_bit_cast(bf16x8, ta);

    // ---- PV from LDS buf cur ----
    #pragma unroll
    for (int n = 0; n < 8; ++n) {
      bf16x8 vb = *(const bf16x8*)&kb[VTOFF + (n * 16 + l15) * VTSTR + q4 * 8];
      O1[n] = __builtin_amdgcn_mfma_f32_16x16x32_bf16(aw, vb, O1[n], 0, 0, 0);
      O2[n] = __builtin_amdgcn_mfma_f32_16x16x32_bf16(at, vb, O2[n], 0, 0, 0);
    }

    // ---- drain reg set `nxt` (tile kt+1, loaded last body) into LDS nxt ----
    *(bf16x8*)&nb[kr_st * KSTR + kc_st]     = kreg[nxt][0];
    *(bf16x8*)&nb[kr_st * KSTR + kc_st + 8] = kreg[nxt][1];
    *(bf16x8*)&nb[VTOFF + vf_st * VTSTR + vh_st]     = vreg[nxt][0];
    *(bf16x8*)&nb[VTOFF + vf_st * VTSTR + vh_st + 8] = vreg[nxt][1];

    // barrier draining ONLY LDS: in-flight VMEM prefetches survive
    asm volatile("s_waitcnt lgkmcnt(0)\n\ts_barrier" ::: "memory");
  }

  // ---- epilogue ----
  lsum += __shfl_xor(lsum, 16, 64);
  lsum += __shfl_xor(lsum, 32, 64);

  if (SPLIT) {
    // partial store: O1, O2 raw + per-row lsum
    if (q4 == 0) lsp[(half * B_ + b) * QL + qrow] = lsum;
    #pragma unroll
    for (int n = 0; n < 8; ++n) {
      #pragma unroll
      for (int r = 0; r < 4; ++r) {
        const int qg_ = qbase + w * 16 + q4 * 4 + r;
        const long long idx =
            ((long long)((half * B_ + b) * QL + qg_)) * FD + n * 16 + l15;
        __builtin_nontemporal_store(O1[n][r], o1p + idx);
        __builtin_nontemporal_store(O2[n][r], o2p + idx);
      }
    }
  } else {
    float linv[4];
    #pragma unroll
    for (int r = 0; r < 4; ++r) linv[r] = 1.0f / __shfl(lsum, q4 * 4 + r, 64);
    #pragma unroll
    for (int n = 0; n < 8; ++n) {
      #pragma unroll
      for (int r = 0; r < 4; ++r) {
        const int qg_ = qbase + w * 16 + q4 * 4 + r;
        const int f   = n * 16 + l15;
        float val = O1[n][r] * linv[r] - O2[n][r];
        __builtin_nontemporal_store(val, outp + ((long long)(b * QL + qg_)) * FD + f);
      }
    }
  }
}

// ---- combine: out = (O1h0+O1h1)/(l0+l1) - (O2h0+O2h1) ----
#define HALFE (B_*QL*FD/4)   // f32x4 elems per half
__global__ __launch_bounds__(256) void combine(const float* __restrict__ o1p,
                                               const float* __restrict__ o2p,
                                               const float* __restrict__ lsp,
                                               float* __restrict__ outp) {
  const int e = blockIdx.x * 256 + threadIdx.x;   // f32x4 index
  const int row = e >> 5;                         // b*QL + q   (FD/4 = 32)
  const float li = 1.0f / (lsp[row] + lsp[B_ * QL + row]);
  f32x4 a0 = __builtin_nontemporal_load((const f32x4*)o1p + e);
  f32x4 a1 = __builtin_nontemporal_load((const f32x4*)o1p + HALFE + e);
  f32x4 b0 = __builtin_nontemporal_load((const f32x4*)o2p + e);
  f32x4 b1 = __builtin_nontemporal_load((const f32x4*)o2p + HALFE + e);
  f32x4 o;
  o[0] = (a0[0] + a1[0]) * li - (b0[0] + b1[0]);
  o[1] = (a0[1] + a1[1]) * li - (b0[1] + b1[1]);
  o[2] = (a0[2] + a1[2]) * li - (b0[2] + b1[2]);
  o[3] = (a0[3] + a1[3]) * li - (b0[3] + b1[3]);
  __builtin_nontemporal_store(o, (f32x4*)outp + e);
}

extern "C" void kernel_launch(void* const* d_in, const int* in_sizes, int n_in,
                              void* d_out, int out_size, void* d_ws, size_t ws_size,
                              hipStream_t stream) {
  const float* q   = (const float*)d_in[0];
  const float* k   = (const float*)d_in[1];
  const float* v   = (const float*)d_in[2];
  const float* cq  = (const float*)d_in[3];
  const float* ck  = (const float*)d_in[4];
  const int*   am  = (const int*)d_in[5];
  const int*   alm = (const int*)d_in[6];
  const float* bs  = (const float*)d_in[7];
  const float* rm  = (const float*)d_in[8];
  float*       out = (float*)d_out;

  unsigned short* kb = (unsigned short*)d_ws;            // 8 MB bf16 K
  unsigned short* vt = kb + WS_HALF;                     // 8 MB bf16 V^T tiles

  hipLaunchKernelGGL(conv_k,  dim3(WS_HALF / 1024), dim3(256), 0, stream, k, kb);
  hipLaunchKernelGGL(conv_vt, dim3(B_ * 64),        dim3(256), 0, stream, v, vt);

  const size_t conv_bytes = (size_t)2 * WS_HALF * sizeof(unsigned short); // 16.8 MB
  const size_t oele = (size_t)2 * B_ * QL * FD;                           // per-matrix (2 halves)
  const size_t need = conv_bytes + 2 * oele * sizeof(float)
                    + (size_t)2 * B_ * QL * sizeof(float);                // ~84 MB
  float* o1p = (float*)((char*)d_ws + conv_bytes);
  float* o2p = o1p + oele;
  float* lsp = o2p + oele;

  if (ws_size >= need) {
    hipLaunchKernelGGL((alibi_attn<1>), dim3(2 * B_ * (QL / BQ)), dim3(256), 0, stream,
                       kb, vt, q, cq, ck, am, alm, bs, rm, out, o1p, o2p, lsp);
    hipLaunchKernelGGL(combine, dim3(B_ * QL * FD / 4 / 256), dim3(256), 0, stream,
                       o1p, o2p, lsp, out);
  } else {
    hipLaunchKernelGGL((alibi_attn<0>), dim3(B_ * (QL / BQ)), dim3(256), 0, stream,
                       kb, vt, q, cq, ck, am, alm, bs, rm, out, o1p, o2p, lsp);
  }
}

// Round 4
// 822.295 us; speedup vs baseline: 1.3039x; 1.3039x over previous
//
#include <hip/hip_runtime.h>
#include <stdint.h>

#define B_  16
#define QL  2048
#define KL  2048
#define FD  128
#define BQ  64
#define BK  32
#define NSTEP (KL/BK)

#define KSTR  136        // K-tile LDS row stride (shorts)
#define VTOFF 4352       // 32*136
#define VTSTR 36         // V^T LDS row stride (shorts); b128 reads conflict-free
#define BUFS  8960       // 4352 + 128*36 shorts per buffer
#define WS_HALF (B_*KL*FD)   // shorts per converted array (8 MB)

typedef __attribute__((ext_vector_type(8))) short bf16x8;
typedef __attribute__((ext_vector_type(4))) float f32x4;
typedef __attribute__((ext_vector_type(4))) int   i32x4;
typedef __attribute__((ext_vector_type(4))) unsigned int u32x4;

__device__ __forceinline__ unsigned short f2b(float f) {
  union { float f; unsigned u; } x; x.f = f;
  return (unsigned short)((x.u + 0x8000u) >> 16);
}

// pack two f32 -> one dword of two bf16 (lo = first arg)
__device__ __forceinline__ unsigned cvt_pk_bf16(float lo, float hi) {
  unsigned r;
  asm("v_cvt_pk_bf16_f32 %0, %1, %2" : "=v"(r) : "v"(lo), "v"(hi));
  return r;
}

// ---- pre-pass 1: K fp32 -> bf16, same layout ----
__global__ __launch_bounds__(256) void conv_k(const float* __restrict__ kp,
                                              unsigned short* __restrict__ kb) {
  int idx = (blockIdx.x * 256 + threadIdx.x) * 4;
  float4 u = *(const float4*)(kp + idx);
  ushort4 s4; s4.x = f2b(u.x); s4.y = f2b(u.y); s4.z = f2b(u.z); s4.w = f2b(u.w);
  *(ushort4*)(kb + idx) = s4;
}

// ---- pre-pass 2: V fp32 [b][k][f] -> bf16 tiled-transposed [b][kt][f][32] ----
__global__ __launch_bounds__(256) void conv_vt(const float* __restrict__ vp,
                                               unsigned short* __restrict__ vt) {
  __shared__ float tl[32 * 132];
  const int t = threadIdx.x, b = blockIdx.x >> 6, kt = blockIdx.x & 63;
  const int r = t >> 3, f0 = (t & 7) * 16;
  const float* src = vp + ((long long)(b * KL + kt * 32 + r)) * FD + f0;
  #pragma unroll
  for (int i = 0; i < 4; ++i)
    *(float4*)&tl[r * 132 + f0 + 4 * i] = *(const float4*)(src + 4 * i);
  __syncthreads();
  const int f = t >> 1, half = t & 1;
  bf16x8 o0, o1;
  #pragma unroll
  for (int j = 0; j < 8; ++j)  o0[j] = (short)f2b(tl[(half * 16 + j) * 132 + f]);
  #pragma unroll
  for (int j = 0; j < 8; ++j)  o1[j] = (short)f2b(tl[(half * 16 + 8 + j) * 132 + f]);
  unsigned short* dst = vt + ((long long)((b * 64 + kt) * FD + f)) * 32 + half * 16;
  *(bf16x8*)dst = o0;
  *(bf16x8*)(dst + 8) = o1;
}

// out = (sum_k !attn*e^s*V)/l - sum_k !attn*!alibi*d*bscale*V,  l = sum_k e^s
//
// R4: occupancy 3 waves/SIMD (R3's 4-wave attempt spilled: unified VGPR need
// ~168 > 512/4=128 cap -> 2.3 GB scratch traffic). Cap 512/3=168; register
// diet to fit: K/V reg pipeline dist-2 -> dist-1 (16 regs), ck coords loaded
// in-body (not double-buffered, L2-resident tile). Masks keep dist-1 dbuf
// (537 MB HBM stream, needs full-body latency cover).
template<int SPLIT>
__global__ __launch_bounds__(256, 3) void alibi_attn(
    const unsigned short* __restrict__ kbp,   // bf16 K [b][k][f]
    const unsigned short* __restrict__ vtp,   // bf16 V^T tiles [b][kt][f][32]
    const float* __restrict__ qp,
    const float* __restrict__ cqp,
    const float* __restrict__ ckp,
    const int* __restrict__ amp,
    const int* __restrict__ almp,
    const float* __restrict__ bsp,
    const float* __restrict__ rmp,
    float* __restrict__ outp,
    float* __restrict__ o1p,
    float* __restrict__ o2p,
    float* __restrict__ lsp)
{
  __shared__ unsigned short kv[2 * BUFS];            // 35 KB K + V^T dbuf

  const int NT = SPLIT ? (NSTEP / 2) : NSTEP;

  const int t    = threadIdx.x;
  const int w    = t >> 6;
  const int lane = t & 63;
  const int l15  = lane & 15;
  const int q4   = lane >> 4;

  const int bid  = blockIdx.x;
  const int half = SPLIT ? (bid >> 9) : 0;
  const int bid5 = bid & 511;
  const int xcd  = bid5 & 7, slot = bid5 >> 3;
  const int b    = (xcd << 1) | (slot >> 5);
  const int qbase = (slot & 31) * BQ;
  const int kt0  = half * NT;

  const float bscale = bsp[0] / rmp[0];
  const float sl2 = 0.08838834764831845f * 1.44269504089f;  // scale*log2(e)

  const int kr_st = t >> 3, kc_st = (t & 7) * 16;  // K staging
  const int vf_st = t >> 1, vh_st = (t & 1) * 16;  // V staging

  // ---- prologue: Q tile -> LDS buf0 (transient), grab B-frags + coords ----
  {
    const float* qg = qp + ((long long)(b * QL + qbase)) * FD;
    #pragma unroll
    for (int i = 0; i < 8; ++i) {
      int idx = t + 256 * i;
      float4 u = ((const float4*)qg)[idx];
      int row = idx >> 5, col = (idx & 31) * 4;
      ushort4 s4; s4.x = f2b(u.x); s4.y = f2b(u.y); s4.z = f2b(u.z); s4.w = f2b(u.w);
      *(ushort4*)&kv[row * KSTR + col] = s4;
    }
  }
  __syncthreads();
  bf16x8 qfrag[4];
  {
    const int m = w * 16 + l15;
    #pragma unroll
    for (int fs = 0; fs < 4; ++fs)
      qfrag[fs] = *(const bf16x8*)&kv[m * KSTR + fs * 32 + q4 * 8];
  }
  // this lane's q-row (swapped layout: q = l15 within the wave's 16 rows)
  const int qrow = qbase + w * 16 + l15;
  float cqx, cqy;
  {
    float2 c2 = *(const float2*)(cqp + ((long long)(b * QL + qrow)) * 2);
    cqx = c2.x; cqy = c2.y;
  }
  const long long mrow = (long long)(b * QL + qrow) * KL;
  __syncthreads();

  const unsigned short* kgb = kbp + (long long)b * KL * FD;
  const unsigned short* vgb = vtp + (long long)b * KL * FD;

  // ---- masks step 0 (regs), K/V tile kt0 -> LDS buf0 ----
  i32x4 amv[2][2], alv[2][2];          // [set][s], component r
  const int klane0 = 4 * q4;           // lane's k_local base (s adds 16)
  #pragma unroll
  for (int s = 0; s < 2; ++s) {
    const int k0 = kt0 * BK + s * 16 + klane0;
    amv[0][s] = __builtin_nontemporal_load((const i32x4*)(amp + mrow + k0));
    alv[0][s] = __builtin_nontemporal_load((const i32x4*)(almp + mrow + k0));
  }
  {
    bf16x8 k0l = *(const bf16x8*)(kgb + (kt0 * BK + kr_st) * FD + kc_st);
    bf16x8 k1l = *(const bf16x8*)(kgb + (kt0 * BK + kr_st) * FD + kc_st + 8);
    bf16x8 v0l = *(const bf16x8*)(vgb + kt0 * (BK * FD) + t * 16);
    bf16x8 v1l = *(const bf16x8*)(vgb + kt0 * (BK * FD) + t * 16 + 8);
    *(bf16x8*)&kv[kr_st * KSTR + kc_st]     = k0l;
    *(bf16x8*)&kv[kr_st * KSTR + kc_st + 8] = k1l;
    *(bf16x8*)&kv[VTOFF + vf_st * VTSTR + vh_st]     = v0l;
    *(bf16x8*)&kv[VTOFF + vf_st * VTSTR + vh_st + 8] = v1l;
  }
  __syncthreads();

  f32x4 O1[8], O2[8];
  #pragma unroll
  for (int n = 0; n < 8; ++n) {
    O1[n] = (f32x4){0.f, 0.f, 0.f, 0.f};
    O2[n] = (f32x4){0.f, 0.f, 0.f, 0.f};
  }
  float lsum = 0.f;

  // cross-lane gather sources for the in-register P/T transpose
  const int srcA = l15 + ((q4 & 1) << 5);
  const int srcB = srcA + 16;
  const bool lowhalf = (q4 < 2);

  bf16x8 kreg[2], vreg[2];   // single-set dist-1 K/V pipeline

  #pragma unroll 2
  for (int kt = 0; kt < NT; ++kt) {
    const int cur = kt & 1, nxt = cur ^ 1;
    const unsigned short* kb = kv + cur * BUFS;
    unsigned short*       nb = kv + nxt * BUFS;

    // ---- issue K/V tile kt+1 loads (drained at bottom of THIS body) ----
    const int ktf = kt0 + ((kt + 1 < NT) ? (kt + 1) : (NT - 1));
    kreg[0] = *(const bf16x8*)(kgb + (ktf * BK + kr_st) * FD + kc_st);
    kreg[1] = *(const bf16x8*)(kgb + (ktf * BK + kr_st) * FD + kc_st + 8);
    vreg[0] = *(const bf16x8*)(vgb + ktf * (BK * FD) + t * 16);
    vreg[1] = *(const bf16x8*)(vgb + ktf * (BK * FD) + t * 16 + 8);

    // ---- masks for step kt+1 (dist-1, vector loads, HBM stream) ----
    #pragma unroll
    for (int s = 0; s < 2; ++s) {
      const int kg = ktf * BK + s * 16 + klane0;
      amv[nxt][s] = __builtin_nontemporal_load((const i32x4*)(amp + mrow + kg));
      alv[nxt][s] = __builtin_nontemporal_load((const i32x4*)(almp + mrow + kg));
    }

    // ---- ck coords for CURRENT step (L2-resident tile, covered by QK^T) ----
    f32x4 ckc[2][2];
    {
      const int ktc = (kt0 + kt) * BK;
      #pragma unroll
      for (int s = 0; s < 2; ++s) {
        const long long cb = ((long long)(b * KL + ktc + s * 16 + klane0)) * 2;
        ckc[s][0] = *(const f32x4*)(ckp + cb);
        ckc[s][1] = *(const f32x4*)(ckp + cb + 4);
      }
    }

    // ---- QK^T (SWAPPED: A=K, B=Q) over F=128 from LDS buf cur ----
    // lane holds S[k = s*16 + 4*q4 + r][q = l15]
    f32x4 S0 = (f32x4){0.f, 0.f, 0.f, 0.f};
    f32x4 S1 = (f32x4){0.f, 0.f, 0.f, 0.f};
    #pragma unroll
    for (int fs = 0; fs < 4; ++fs) {
      bf16x8 kb0 = *(const bf16x8*)&kb[(l15)      * KSTR + fs * 32 + q4 * 8];
      bf16x8 kb1 = *(const bf16x8*)&kb[(16 + l15) * KSTR + fs * 32 + q4 * 8];
      S0 = __builtin_amdgcn_mfma_f32_16x16x32_bf16(kb0, qfrag[fs], S0, 0, 0, 0);
      S1 = __builtin_amdgcn_mfma_f32_16x16x32_bf16(kb1, qfrag[fs], S1, 0, 0, 0);
    }

    // ---- transform (all 8 elements belong to q = qrow) ----
    float wvv[2][4], tvv[2][4];
    #pragma unroll
    for (int s = 0; s < 2; ++s) {
      const f32x4 Sv = s ? S1 : S0;
      #pragma unroll
      for (int r = 0; r < 4; ++r) {
        float e = __builtin_amdgcn_exp2f(Sv[r] * sl2);
        lsum += e;
        const float ckx = ckc[s][r >> 1][(r & 1) * 2];
        const float cky = ckc[s][r >> 1][(r & 1) * 2 + 1];
        float dx = cqx - ckx, dy = cqy - cky;
        float d  = sqrtf(fmaf(dx, dx, dy * dy)) * bscale;
        int am = amv[cur][s][r], al = alv[cur][s][r];
        wvv[s][r] = am ? 0.f : e;
        tvv[s][r] = (am | al) ? 0.f : d;
      }
    }

    // ---- pack to bf16 + in-register transpose into PV A-frag layout ----
    unsigned aX0 = cvt_pk_bf16(wvv[0][0], wvv[0][1]);
    unsigned aX1 = cvt_pk_bf16(wvv[0][2], wvv[0][3]);
    unsigned aX2 = cvt_pk_bf16(wvv[1][0], wvv[1][1]);
    unsigned aX3 = cvt_pk_bf16(wvv[1][2], wvv[1][3]);
    unsigned tX0 = cvt_pk_bf16(tvv[0][0], tvv[0][1]);
    unsigned tX1 = cvt_pk_bf16(tvv[0][2], tvv[0][3]);
    unsigned tX2 = cvt_pk_bf16(tvv[1][0], tvv[1][1]);
    unsigned tX3 = cvt_pk_bf16(tvv[1][2], tvv[1][3]);

    u32x4 wa, ta;
    {
      int y0, y2;
      y0 = __shfl((int)aX0, srcA); y2 = __shfl((int)aX2, srcA);
      wa[0] = (unsigned)(lowhalf ? y0 : y2);
      y0 = __shfl((int)aX1, srcA); y2 = __shfl((int)aX3, srcA);
      wa[1] = (unsigned)(lowhalf ? y0 : y2);
      y0 = __shfl((int)aX0, srcB); y2 = __shfl((int)aX2, srcB);
      wa[2] = (unsigned)(lowhalf ? y0 : y2);
      y0 = __shfl((int)aX1, srcB); y2 = __shfl((int)aX3, srcB);
      wa[3] = (unsigned)(lowhalf ? y0 : y2);
      y0 = __shfl((int)tX0, srcA); y2 = __shfl((int)tX2, srcA);
      ta[0] = (unsigned)(lowhalf ? y0 : y2);
      y0 = __shfl((int)tX1, srcA); y2 = __shfl((int)tX3, srcA);
      ta[1] = (unsigned)(lowhalf ? y0 : y2);
      y0 = __shfl((int)tX0, srcB); y2 = __shfl((int)tX2, srcB);
      ta[2] = (unsigned)(lowhalf ? y0 : y2);
      y0 = __shfl((int)tX1, srcB); y2 = __shfl((int)tX3, srcB);
      ta[3] = (unsigned)(lowhalf ? y0 : y2);
    }
    bf16x8 aw = __builtin_bit_cast(bf16x8, wa);
    bf16x8 at = __builtin_bit_cast(bf16x8, ta);

    // ---- PV from LDS buf cur ----
    #pragma unroll
    for (int n = 0; n < 8; ++n) {
      bf16x8 vb = *(const bf16x8*)&kb[VTOFF + (n * 16 + l15) * VTSTR + q4 * 8];
      O1[n] = __builtin_amdgcn_mfma_f32_16x16x32_bf16(aw, vb, O1[n], 0, 0, 0);
      O2[n] = __builtin_amdgcn_mfma_f32_16x16x32_bf16(at, vb, O2[n], 0, 0, 0);
    }

    // ---- drain K/V regs (tile kt+1, issued at top of this body) -> LDS nxt ----
    *(bf16x8*)&nb[kr_st * KSTR + kc_st]     = kreg[0];
    *(bf16x8*)&nb[kr_st * KSTR + kc_st + 8] = kreg[1];
    *(bf16x8*)&nb[VTOFF + vf_st * VTSTR + vh_st]     = vreg[0];
    *(bf16x8*)&nb[VTOFF + vf_st * VTSTR + vh_st + 8] = vreg[1];

    // barrier draining ONLY LDS: in-flight VMEM (masks) survives
    asm volatile("s_waitcnt lgkmcnt(0)\n\ts_barrier" ::: "memory");
  }

  // ---- epilogue ----
  lsum += __shfl_xor(lsum, 16, 64);
  lsum += __shfl_xor(lsum, 32, 64);

  if (SPLIT) {
    // partial store: O1, O2 raw + per-row lsum
    if (q4 == 0) lsp[(half * B_ + b) * QL + qrow] = lsum;
    #pragma unroll
    for (int n = 0; n < 8; ++n) {
      #pragma unroll
      for (int r = 0; r < 4; ++r) {
        const int qg_ = qbase + w * 16 + q4 * 4 + r;
        const long long idx =
            ((long long)((half * B_ + b) * QL + qg_)) * FD + n * 16 + l15;
        __builtin_nontemporal_store(O1[n][r], o1p + idx);
        __builtin_nontemporal_store(O2[n][r], o2p + idx);
      }
    }
  } else {
    float linv[4];
    #pragma unroll
    for (int r = 0; r < 4; ++r) linv[r] = 1.0f / __shfl(lsum, q4 * 4 + r, 64);
    #pragma unroll
    for (int n = 0; n < 8; ++n) {
      #pragma unroll
      for (int r = 0; r < 4; ++r) {
        const int qg_ = qbase + w * 16 + q4 * 4 + r;
        const int f   = n * 16 + l15;
        float val = O1[n][r] * linv[r] - O2[n][r];
        __builtin_nontemporal_store(val, outp + ((long long)(b * QL + qg_)) * FD + f);
      }
    }
  }
}

// ---- combine: out = (O1h0+O1h1)/(l0+l1) - (O2h0+O2h1) ----
#define HALFE (B_*QL*FD/4)   // f32x4 elems per half
__global__ __launch_bounds__(256) void combine(const float* __restrict__ o1p,
                                               const float* __restrict__ o2p,
                                               const float* __restrict__ lsp,
                                               float* __restrict__ outp) {
  const int e = blockIdx.x * 256 + threadIdx.x;   // f32x4 index
  const int row = e >> 5;                         // b*QL + q   (FD/4 = 32)
  const float li = 1.0f / (lsp[row] + lsp[B_ * QL + row]);
  f32x4 a0 = __builtin_nontemporal_load((const f32x4*)o1p + e);
  f32x4 a1 = __builtin_nontemporal_load((const f32x4*)o1p + HALFE + e);
  f32x4 b0 = __builtin_nontemporal_load((const f32x4*)o2p + e);
  f32x4 b1 = __builtin_nontemporal_load((const f32x4*)o2p + HALFE + e);
  f32x4 o;
  o[0] = (a0[0] + a1[0]) * li - (b0[0] + b1[0]);
  o[1] = (a0[1] + a1[1]) * li - (b0[1] + b1[1]);
  o[2] = (a0[2] + a1[2]) * li - (b0[2] + b1[2]);
  o[3] = (a0[3] + a1[3]) * li - (b0[3] + b1[3]);
  __builtin_nontemporal_store(o, (f32x4*)outp + e);
}

extern "C" void kernel_launch(void* const* d_in, const int* in_sizes, int n_in,
                              void* d_out, int out_size, void* d_ws, size_t ws_size,
                              hipStream_t stream) {
  const float* q   = (const float*)d_in[0];
  const float* k   = (const float*)d_in[1];
  const float* v   = (const float*)d_in[2];
  const float* cq  = (const float*)d_in[3];
  const float* ck  = (const float*)d_in[4];
  const int*   am  = (const int*)d_in[5];
  const int*   alm = (const int*)d_in[6];
  const float* bs  = (const float*)d_in[7];
  const float* rm  = (const float*)d_in[8];
  float*       out = (float*)d_out;

  unsigned short* kb = (unsigned short*)d_ws;            // 8 MB bf16 K
  unsigned short* vt = kb + WS_HALF;                     // 8 MB bf16 V^T tiles

  hipLaunchKernelGGL(conv_k,  dim3(WS_HALF / 1024), dim3(256), 0, stream, k, kb);
  hipLaunchKernelGGL(conv_vt, dim3(B_ * 64),        dim3(256), 0, stream, v, vt);

  const size_t conv_bytes = (size_t)2 * WS_HALF * sizeof(unsigned short); // 16.8 MB
  const size_t oele = (size_t)2 * B_ * QL * FD;                           // per-matrix (2 halves)
  const size_t need = conv_bytes + 2 * oele * sizeof(float)
                    + (size_t)2 * B_ * QL * sizeof(float);                // ~84 MB
  float* o1p = (float*)((char*)d_ws + conv_bytes);
  float* o2p = o1p + oele;
  float* lsp = o2p + oele;

  if (ws_size >= need) {
    hipLaunchKernelGGL((alibi_attn<1>), dim3(2 * B_ * (QL / BQ)), dim3(256), 0, stream,
                       kb, vt, q, cq, ck, am, alm, bs, rm, out, o1p, o2p, lsp);
    hipLaunchKernelGGL(combine, dim3(B_ * QL * FD / 4 / 256), dim3(256), 0, stream,
                       o1p, o2p, lsp, out);
  } else {
    hipLaunchKernelGGL((alibi_attn<0>), dim3(B_ * (QL / BQ)), dim3(256), 0, stream,
                       kb, vt, q, cq, ck, am, alm, bs, rm, out, o1p, o2p, lsp);
  }
}

// Round 5
// 754.399 us; speedup vs baseline: 1.4213x; 1.0900x over previous
//
#include <hip/hip_runtime.h>
#include <stdint.h>

#define B_  16
#define QL  2048
#define KL  2048
#define FD  128
#define BQ  64
#define BK  32
#define NSTEP (KL/BK)

#define KSTR  136        // K-tile LDS row stride (shorts)
#define VTOFF 4352       // 32*136
#define VTSTR 36         // V^T LDS row stride (shorts); b128 reads conflict-free
#define BUFS  8960       // 4352 + 128*36 shorts per buffer
#define WS_HALF (B_*KL*FD)   // shorts per converted array (8 MB)
#define NROW  (B_*QL)        // 32768 mask rows
#define WPR   (KL/32)        // 64 packed words per row

typedef __attribute__((ext_vector_type(8))) short bf16x8;
typedef __attribute__((ext_vector_type(4))) float f32x4;
typedef __attribute__((ext_vector_type(4))) int   i32x4;
typedef __attribute__((ext_vector_type(4))) unsigned int u32x4;
typedef __attribute__((ext_vector_type(2))) unsigned int u32x2;

__device__ __forceinline__ unsigned short f2b(float f) {
  union { float f; unsigned u; } x; x.f = f;
  return (unsigned short)((x.u + 0x8000u) >> 16);
}

// pack two f32 -> one dword of two bf16 (lo = first arg)
__device__ __forceinline__ unsigned cvt_pk_bf16(float lo, float hi) {
  unsigned r;
  asm("v_cvt_pk_bf16_f32 %0, %1, %2" : "=v"(r) : "v"(lo), "v"(hi));
  return r;
}

// ---- pre-pass 1: K fp32 -> bf16, same layout ----
__global__ __launch_bounds__(256) void conv_k(const float* __restrict__ kp,
                                              unsigned short* __restrict__ kb) {
  int idx = (blockIdx.x * 256 + threadIdx.x) * 4;
  float4 u = *(const float4*)(kp + idx);
  ushort4 s4; s4.x = f2b(u.x); s4.y = f2b(u.y); s4.z = f2b(u.z); s4.w = f2b(u.w);
  *(ushort4*)(kb + idx) = s4;
}

// ---- pre-pass 2: V fp32 [b][k][f] -> bf16 tiled-transposed [b][kt][f][32] ----
__global__ __launch_bounds__(256) void conv_vt(const float* __restrict__ vp,
                                               unsigned short* __restrict__ vt) {
  __shared__ float tl[32 * 132];
  const int t = threadIdx.x, b = blockIdx.x >> 6, kt = blockIdx.x & 63;
  const int r = t >> 3, f0 = (t & 7) * 16;
  const float* src = vp + ((long long)(b * KL + kt * 32 + r)) * FD + f0;
  #pragma unroll
  for (int i = 0; i < 4; ++i)
    *(float4*)&tl[r * 132 + f0 + 4 * i] = *(const float4*)(src + 4 * i);
  __syncthreads();
  const int f = t >> 1, half = t & 1;
  bf16x8 o0, o1;
  #pragma unroll
  for (int j = 0; j < 8; ++j)  o0[j] = (short)f2b(tl[(half * 16 + j) * 132 + f]);
  #pragma unroll
  for (int j = 0; j < 8; ++j)  o1[j] = (short)f2b(tl[(half * 16 + 8 + j) * 132 + f]);
  unsigned short* dst = vt + ((long long)((b * 64 + kt) * FD + f)) * 32 + half * 16;
  *(bf16x8*)dst = o0;
  *(bf16x8*)(dst + 8) = o1;
}

// ---- pre-pass 3: bit-pack masks. 537 MB int32 -> 16.8 MB {am, am|al} words.
// One wave per (b,q) row; coalesced 4B loads; __ballot packs 64 k's at once.
__global__ __launch_bounds__(256) void pack_masks(const int* __restrict__ amp,
                                                  const int* __restrict__ almp,
                                                  u32x2* __restrict__ out) {
  const int row  = blockIdx.x * 4 + (threadIdx.x >> 6);
  const int lane = threadIdx.x & 63;
  const long long base = (long long)row * KL;
  u32x2* orow = out + (long long)row * WPR;
  #pragma unroll 4
  for (int j = 0; j < 32; ++j) {
    int a = __builtin_nontemporal_load(amp  + base + j * 64 + lane);
    int l = __builtin_nontemporal_load(almp + base + j * 64 + lane);
    unsigned long long ab = __ballot(a != 0);
    unsigned long long ob = ab | __ballot(l != 0);   // am | al
    if (lane == 0) {
      u32x4 pk;
      pk[0] = (unsigned)ab;         pk[1] = (unsigned)ob;          // word 2j
      pk[2] = (unsigned)(ab >> 32); pk[3] = (unsigned)(ob >> 32);  // word 2j+1
      *(u32x4*)&orow[2 * j] = pk;
    }
  }
}

// out = (sum_k !attn*e^s*V)/l - sum_k !attn*!alibi*d*bscale*V,  l = sum_k e^s
//
// R5: masks consumed as packed bits (8 B/lane/step, L2-resident) instead of
// 2 KB/wave/step of HBM-latency int32 loads — the per-step latency dependency
// that capped R1 at 1.2 TB/s effective is gone. Structure = proven R1: grid
// 512, dist-2 K/V reg pipeline, dist-1 ck coords, lgkm-only barrier.
__global__ __launch_bounds__(256, 2) void alibi_attn(
    const unsigned short* __restrict__ kbp,   // bf16 K [b][k][f]
    const unsigned short* __restrict__ vtp,   // bf16 V^T tiles [b][kt][f][32]
    const u32x2* __restrict__ pmp,            // packed {am, am|al} [row][kt]
    const float* __restrict__ qp,
    const float* __restrict__ cqp,
    const float* __restrict__ ckp,
    const float* __restrict__ bsp,
    const float* __restrict__ rmp,
    float* __restrict__ outp)
{
  __shared__ unsigned short kv[2 * BUFS];            // 35 KB K + V^T dbuf

  const int t    = threadIdx.x;
  const int w    = t >> 6;
  const int lane = t & 63;
  const int l15  = lane & 15;
  const int q4   = lane >> 4;

  const int bid  = blockIdx.x;
  const int xcd  = bid & 7, slot = bid >> 3;
  const int b    = (xcd << 1) | (slot >> 5);
  const int qbase = (slot & 31) * BQ;

  const float bscale = bsp[0] / rmp[0];
  const float sl2 = 0.08838834764831845f * 1.44269504089f;  // scale*log2(e)

  const int kr_st = t >> 3, kc_st = (t & 7) * 16;  // K staging
  const int vf_st = t >> 1, vh_st = (t & 1) * 16;  // V staging

  // ---- prologue: Q tile -> LDS buf0 (transient), grab B-frags + coords ----
  {
    const float* qg = qp + ((long long)(b * QL + qbase)) * FD;
    #pragma unroll
    for (int i = 0; i < 8; ++i) {
      int idx = t + 256 * i;
      float4 u = ((const float4*)qg)[idx];
      int row = idx >> 5, col = (idx & 31) * 4;
      ushort4 s4; s4.x = f2b(u.x); s4.y = f2b(u.y); s4.z = f2b(u.z); s4.w = f2b(u.w);
      *(ushort4*)&kv[row * KSTR + col] = s4;
    }
  }
  __syncthreads();
  bf16x8 qfrag[4];
  {
    const int m = w * 16 + l15;
    #pragma unroll
    for (int fs = 0; fs < 4; ++fs)
      qfrag[fs] = *(const bf16x8*)&kv[m * KSTR + fs * 32 + q4 * 8];
  }
  // this lane's q-row (swapped layout: q = l15 within the wave's 16 rows)
  const int qrow = qbase + w * 16 + l15;
  float cqx, cqy;
  {
    float2 c2 = *(const float2*)(cqp + ((long long)(b * QL + qrow)) * 2);
    cqx = c2.x; cqy = c2.y;
  }
  const long long mwrow = (long long)(b * QL + qrow) * WPR;
  __syncthreads();

  const unsigned short* kgb = kbp + (long long)b * KL * FD;
  const unsigned short* vgb = vtp + (long long)b * KL * FD;

  // ---- masks step 0 (packed word), coords step 0, K/V tile 0+1 staging ----
  u32x2 mw[2];                         // packed {am, am|al} dbuf: 4 regs
  f32x4 ckf[2][2][2];                  // [set][s][pair(r>>1)]: (x,y,x,y)
  bf16x8 kreg[2][2], vreg[2][2];
  const int klane0 = 4 * q4;           // lane's k_local base (s adds 16)
  mw[0] = pmp[mwrow];
  #pragma unroll
  for (int s = 0; s < 2; ++s) {
    const int k0 = s * 16 + klane0;
    ckf[0][s][0] = *(const f32x4*)(ckp + ((long long)(b * KL + k0)) * 2);
    ckf[0][s][1] = *(const f32x4*)(ckp + ((long long)(b * KL + k0)) * 2 + 4);
  }
  {
    bf16x8 k0l = *(const bf16x8*)(kgb + kr_st * FD + kc_st);
    bf16x8 k1l = *(const bf16x8*)(kgb + kr_st * FD + kc_st + 8);
    bf16x8 v0l = *(const bf16x8*)(vgb + t * 16);
    bf16x8 v1l = *(const bf16x8*)(vgb + t * 16 + 8);
    *(bf16x8*)&kv[kr_st * KSTR + kc_st]     = k0l;
    *(bf16x8*)&kv[kr_st * KSTR + kc_st + 8] = k1l;
    *(bf16x8*)&kv[VTOFF + vf_st * VTSTR + vh_st]     = v0l;
    *(bf16x8*)&kv[VTOFF + vf_st * VTSTR + vh_st + 8] = v1l;
    // tile 1 into register set 1 (drained at bottom of body 0)
    kreg[1][0] = *(const bf16x8*)(kgb + (BK + kr_st) * FD + kc_st);
    kreg[1][1] = *(const bf16x8*)(kgb + (BK + kr_st) * FD + kc_st + 8);
    vreg[1][0] = *(const bf16x8*)(vgb + BK * FD + t * 16);
    vreg[1][1] = *(const bf16x8*)(vgb + BK * FD + t * 16 + 8);
  }
  __syncthreads();

  f32x4 O1[8], O2[8];
  #pragma unroll
  for (int n = 0; n < 8; ++n) {
    O1[n] = (f32x4){0.f, 0.f, 0.f, 0.f};
    O2[n] = (f32x4){0.f, 0.f, 0.f, 0.f};
  }
  float lsum = 0.f;

  // cross-lane gather sources for the in-register P/T transpose
  const int srcA = l15 + ((q4 & 1) << 5);
  const int srcB = srcA + 16;
  const bool lowhalf = (q4 < 2);

  #pragma unroll 2
  for (int kt = 0; kt < NSTEP; ++kt) {
    const int cur = kt & 1, nxt = cur ^ 1;
    const unsigned short* kb = kv + cur * BUFS;
    unsigned short*       nb = kv + nxt * BUFS;

    // ---- fill reg set `cur` with tile kt+2 (consumed 2 bodies later) ----
    const int ktf = (kt + 2 < NSTEP) ? (kt + 2) : (NSTEP - 1);
    kreg[cur][0] = *(const bf16x8*)(kgb + (ktf * BK + kr_st) * FD + kc_st);
    kreg[cur][1] = *(const bf16x8*)(kgb + (ktf * BK + kr_st) * FD + kc_st + 8);
    vreg[cur][0] = *(const bf16x8*)(vgb + ktf * (BK * FD) + t * 16);
    vreg[cur][1] = *(const bf16x8*)(vgb + ktf * (BK * FD) + t * 16 + 8);

    // ---- packed mask word + coords for step kt+1 (dist-1) ----
    const int ktm = (kt + 1 < NSTEP) ? (kt + 1) : kt;
    mw[nxt] = pmp[mwrow + ktm];
    #pragma unroll
    for (int s = 0; s < 2; ++s) {
      const int kg = ktm * BK + s * 16 + klane0;
      ckf[nxt][s][0] = *(const f32x4*)(ckp + ((long long)(b * KL + kg)) * 2);
      ckf[nxt][s][1] = *(const f32x4*)(ckp + ((long long)(b * KL + kg)) * 2 + 4);
    }

    // ---- QK^T (SWAPPED: A=K, B=Q) over F=128 from LDS buf cur ----
    // lane holds S[k = s*16 + 4*q4 + r][q = l15]
    f32x4 S0 = (f32x4){0.f, 0.f, 0.f, 0.f};
    f32x4 S1 = (f32x4){0.f, 0.f, 0.f, 0.f};
    #pragma unroll
    for (int fs = 0; fs < 4; ++fs) {
      bf16x8 kb0 = *(const bf16x8*)&kb[(l15)      * KSTR + fs * 32 + q4 * 8];
      bf16x8 kb1 = *(const bf16x8*)&kb[(16 + l15) * KSTR + fs * 32 + q4 * 8];
      S0 = __builtin_amdgcn_mfma_f32_16x16x32_bf16(kb0, qfrag[fs], S0, 0, 0, 0);
      S1 = __builtin_amdgcn_mfma_f32_16x16x32_bf16(kb1, qfrag[fs], S1, 0, 0, 0);
    }

    // ---- transform (all 8 elements belong to q = qrow); mask = bit test ----
    const unsigned ab = mw[cur][0], ob = mw[cur][1];
    float wvv[2][4], tvv[2][4];
    #pragma unroll
    for (int s = 0; s < 2; ++s) {
      const f32x4 Sv = s ? S1 : S0;
      #pragma unroll
      for (int r = 0; r < 4; ++r) {
        float e = __builtin_amdgcn_exp2f(Sv[r] * sl2);
        lsum += e;
        const float ckx = ckf[cur][s][r >> 1][(r & 1) * 2];
        const float cky = ckf[cur][s][r >> 1][(r & 1) * 2 + 1];
        float dx = cqx - ckx, dy = cqy - cky;
        float d  = sqrtf(fmaf(dx, dx, dy * dy)) * bscale;
        const int bit = s * 16 + klane0 + r;
        wvv[s][r] = ((ab >> bit) & 1u) ? 0.f : e;
        tvv[s][r] = ((ob >> bit) & 1u) ? 0.f : d;
      }
    }

    // ---- pack to bf16 + in-register transpose into PV A-frag layout ----
    unsigned aX0 = cvt_pk_bf16(wvv[0][0], wvv[0][1]);
    unsigned aX1 = cvt_pk_bf16(wvv[0][2], wvv[0][3]);
    unsigned aX2 = cvt_pk_bf16(wvv[1][0], wvv[1][1]);
    unsigned aX3 = cvt_pk_bf16(wvv[1][2], wvv[1][3]);
    unsigned tX0 = cvt_pk_bf16(tvv[0][0], tvv[0][1]);
    unsigned tX1 = cvt_pk_bf16(tvv[0][2], tvv[0][3]);
    unsigned tX2 = cvt_pk_bf16(tvv[1][0], tvv[1][1]);
    unsigned tX3 = cvt_pk_bf16(tvv[1][2], tvv[1][3]);

    u32x4 wa, ta;
    {
      int y0, y2;
      y0 = __shfl((int)aX0, srcA); y2 = __shfl((int)aX2, srcA);
      wa[0] = (unsigned)(lowhalf ? y0 : y2);
      y0 = __shfl((int)aX1, srcA); y2 = __shfl((int)aX3, srcA);
      wa[1] = (unsigned)(lowhalf ? y0 : y2);
      y0 = __shfl((int)aX0, srcB); y2 = __shfl((int)aX2, srcB);
      wa[2] = (unsigned)(lowhalf ? y0 : y2);
      y0 = __shfl((int)aX1, srcB); y2 = __shfl((int)aX3, srcB);
      wa[3] = (unsigned)(lowhalf ? y0 : y2);
      y0 = __shfl((int)tX0, srcA); y2 = __shfl((int)tX2, srcA);
      ta[0] = (unsigned)(lowhalf ? y0 : y2);
      y0 = __shfl((int)tX1, srcA); y2 = __shfl((int)tX3, srcA);
      ta[1] = (unsigned)(lowhalf ? y0 : y2);
      y0 = __shfl((int)tX0, srcB); y2 = __shfl((int)tX2, srcB);
      ta[2] = (unsigned)(lowhalf ? y0 : y2);
      y0 = __shfl((int)tX1, srcB); y2 = __shfl((int)tX3, srcB);
      ta[3] = (unsigned)(lowhalf ? y0 : y2);
    }
    bf16x8 aw = __builtin_bit_cast(bf16x8, wa);
    bf16x8 at = __builtin_bit_cast(bf16x8, ta);

    // ---- PV from LDS buf cur ----
    #pragma unroll
    for (int n = 0; n < 8; ++n) {
      bf16x8 vb = *(const bf16x8*)&kb[VTOFF + (n * 16 + l15) * VTSTR + q4 * 8];
      O1[n] = __builtin_amdgcn_mfma_f32_16x16x32_bf16(aw, vb, O1[n], 0, 0, 0);
      O2[n] = __builtin_amdgcn_mfma_f32_16x16x32_bf16(at, vb, O2[n], 0, 0, 0);
    }

    // ---- drain reg set `nxt` (tile kt+1, loaded 2 bodies ago) into LDS nxt ----
    *(bf16x8*)&nb[kr_st * KSTR + kc_st]     = kreg[nxt][0];
    *(bf16x8*)&nb[kr_st * KSTR + kc_st + 8] = kreg[nxt][1];
    *(bf16x8*)&nb[VTOFF + vf_st * VTSTR + vh_st]     = vreg[nxt][0];
    *(bf16x8*)&nb[VTOFF + vf_st * VTSTR + vh_st + 8] = vreg[nxt][1];

    // barrier draining ONLY LDS: in-flight VMEM prefetches survive
    asm volatile("s_waitcnt lgkmcnt(0)\n\ts_barrier" ::: "memory");
  }

  // ---- epilogue: lane-local lsum -> per-row totals, combine, store ----
  lsum += __shfl_xor(lsum, 16, 64);
  lsum += __shfl_xor(lsum, 32, 64);
  float linv[4];
  #pragma unroll
  for (int r = 0; r < 4; ++r) linv[r] = 1.0f / __shfl(lsum, q4 * 4 + r, 64);

  #pragma unroll
  for (int n = 0; n < 8; ++n) {
    #pragma unroll
    for (int r = 0; r < 4; ++r) {
      const int qg_ = qbase + w * 16 + q4 * 4 + r;
      const int f   = n * 16 + l15;
      float val = O1[n][r] * linv[r] - O2[n][r];
      __builtin_nontemporal_store(val, outp + ((long long)(b * QL + qg_)) * FD + f);
    }
  }
}

extern "C" void kernel_launch(void* const* d_in, const int* in_sizes, int n_in,
                              void* d_out, int out_size, void* d_ws, size_t ws_size,
                              hipStream_t stream) {
  const float* q   = (const float*)d_in[0];
  const float* k   = (const float*)d_in[1];
  const float* v   = (const float*)d_in[2];
  const float* cq  = (const float*)d_in[3];
  const float* ck  = (const float*)d_in[4];
  const int*   am  = (const int*)d_in[5];
  const int*   alm = (const int*)d_in[6];
  const float* bs  = (const float*)d_in[7];
  const float* rm  = (const float*)d_in[8];
  float*       out = (float*)d_out;

  unsigned short* kb = (unsigned short*)d_ws;            // 8 MB bf16 K
  unsigned short* vt = kb + WS_HALF;                     // 8 MB bf16 V^T tiles
  u32x2*          pm = (u32x2*)(vt + WS_HALF);           // 16.8 MB packed masks

  hipLaunchKernelGGL(conv_k,     dim3(WS_HALF / 1024), dim3(256), 0, stream, k, kb);
  hipLaunchKernelGGL(conv_vt,    dim3(B_ * 64),        dim3(256), 0, stream, v, vt);
  hipLaunchKernelGGL(pack_masks, dim3(NROW / 4),       dim3(256), 0, stream, am, alm, pm);

  dim3 grid(B_ * (QL / BQ));   // 512 blocks, 2/CU
  dim3 block(256);
  hipLaunchKernelGGL(alibi_attn, grid, block, 0, stream,
                     kb, vt, pm, q, cq, ck, bs, rm, out);
}

// Round 6
// 709.449 us; speedup vs baseline: 1.5113x; 1.0634x over previous
//
#include <hip/hip_runtime.h>
#include <stdint.h>

#define B_  16
#define QL  2048
#define KL  2048
#define FD  128
#define BQ  64
#define BK  32
#define NSTEP (KL/BK)
#define NPAIR (NSTEP/2)

#define KSTR  136        // K-tile LDS row stride (shorts)
#define VTOFF 4352       // 32*136
#define VTSTR 36         // V^T LDS row stride (shorts)
#define BUFS  8960       // 4352 + 128*36 shorts per buffer
#define WS_HALF (B_*KL*FD)   // shorts per converted array (8 MB)

typedef __attribute__((ext_vector_type(8))) short bf16x8;
typedef __attribute__((ext_vector_type(4))) float f32x4;
typedef __attribute__((ext_vector_type(4))) int   i32x4;
typedef __attribute__((ext_vector_type(4))) unsigned int u32x4;

__device__ __forceinline__ unsigned short f2b(float f) {
  union { float f; unsigned u; } x; x.f = f;
  return (unsigned short)((x.u + 0x8000u) >> 16);
}

__device__ __forceinline__ unsigned cvt_pk_bf16(float lo, float hi) {
  unsigned r;
  asm("v_cvt_pk_bf16_f32 %0, %1, %2" : "=v"(r) : "v"(lo), "v"(hi));
  return r;
}

// ---- pre-pass 1: K fp32 -> bf16, same layout ----
__global__ __launch_bounds__(256) void conv_k(const float* __restrict__ kp,
                                              unsigned short* __restrict__ kb) {
  int idx = (blockIdx.x * 256 + threadIdx.x) * 4;
  float4 u = *(const float4*)(kp + idx);
  ushort4 s4; s4.x = f2b(u.x); s4.y = f2b(u.y); s4.z = f2b(u.z); s4.w = f2b(u.w);
  *(ushort4*)(kb + idx) = s4;
}

// ---- pre-pass 2: V fp32 [b][k][f] -> bf16 tiled-transposed [b][kt][f][32] ----
__global__ __launch_bounds__(256) void conv_vt(const float* __restrict__ vp,
                                               unsigned short* __restrict__ vt) {
  __shared__ float tl[32 * 132];
  const int t = threadIdx.x, b = blockIdx.x >> 6, kt = blockIdx.x & 63;
  const int r = t >> 3, f0 = (t & 7) * 16;
  const float* src = vp + ((long long)(b * KL + kt * 32 + r)) * FD + f0;
  #pragma unroll
  for (int i = 0; i < 4; ++i)
    *(float4*)&tl[r * 132 + f0 + 4 * i] = *(const float4*)(src + 4 * i);
  __syncthreads();
  const int f = t >> 1, half = t & 1;
  bf16x8 o0, o1;
  #pragma unroll
  for (int j = 0; j < 8; ++j)  o0[j] = (short)f2b(tl[(half * 16 + j) * 132 + f]);
  #pragma unroll
  for (int j = 0; j < 8; ++j)  o1[j] = (short)f2b(tl[(half * 16 + 8 + j) * 132 + f]);
  unsigned short* dst = vt + ((long long)((b * 64 + kt) * FD + f)) * 32 + half * 16;
  *(bf16x8*)dst = o0;
  *(bf16x8*)(dst + 8) = o1;
}

// digest one k-tile's raw masks+coords into {row-bit-mask, pre-masked packed
// transposed T fragment}. Runs OFF the S-dependent critical path.
__device__ __forceinline__ void digest_tile(
    const i32x4* ram, const i32x4* ral, const f32x4 (*rck)[2],
    float cqx, float cqy, float bscale, int klane0,
    int srcA, int srcB, bool lowhalf,
    unsigned& amw_o, u32x4& ta_o)
{
  unsigned pb = 0, ob = 0;
  #pragma unroll
  for (int s = 0; s < 2; ++s)
    #pragma unroll
    for (int r = 0; r < 4; ++r) {
      const unsigned bm = 1u << (s * 16 + klane0 + r);
      pb |= ram[s][r] ? bm : 0u;
      ob |= (ram[s][r] | ral[s][r]) ? bm : 0u;
    }
  pb |= (unsigned)__shfl_xor((int)pb, 16, 64);
  pb |= (unsigned)__shfl_xor((int)pb, 32, 64);
  ob |= (unsigned)__shfl_xor((int)ob, 16, 64);
  ob |= (unsigned)__shfl_xor((int)ob, 32, 64);

  float tvv[2][4];
  #pragma unroll
  for (int s = 0; s < 2; ++s)
    #pragma unroll
    for (int r = 0; r < 4; ++r) {
      const float ckx = rck[s][r >> 1][(r & 1) * 2];
      const float cky = rck[s][r >> 1][(r & 1) * 2 + 1];
      float dx = cqx - ckx, dy = cqy - cky;
      float d  = sqrtf(fmaf(dx, dx, dy * dy)) * bscale;
      tvv[s][r] = ((ob >> (s * 16 + klane0 + r)) & 1u) ? 0.f : d;
    }
  unsigned tX0 = cvt_pk_bf16(tvv[0][0], tvv[0][1]);
  unsigned tX1 = cvt_pk_bf16(tvv[0][2], tvv[0][3]);
  unsigned tX2 = cvt_pk_bf16(tvv[1][0], tvv[1][1]);
  unsigned tX3 = cvt_pk_bf16(tvv[1][2], tvv[1][3]);
  u32x4 ta;
  {
    int y0, y2;
    y0 = __shfl((int)tX0, srcA, 64); y2 = __shfl((int)tX2, srcA, 64);
    ta[0] = (unsigned)(lowhalf ? y0 : y2);
    y0 = __shfl((int)tX1, srcA, 64); y2 = __shfl((int)tX3, srcA, 64);
    ta[1] = (unsigned)(lowhalf ? y0 : y2);
    y0 = __shfl((int)tX0, srcB, 64); y2 = __shfl((int)tX2, srcB, 64);
    ta[2] = (unsigned)(lowhalf ? y0 : y2);
    y0 = __shfl((int)tX1, srcB, 64); y2 = __shfl((int)tX3, srcB, 64);
    ta[3] = (unsigned)(lowhalf ? y0 : y2);
  }
  amw_o = pb;
  ta_o  = ta;
}

// out = (sum_k !attn*e^s*V)/l - sum_k !attn*!alibi*d*bscale*V,  l = sum_k e^s
//
// R6: ILP-2 pair-bodies on 4 LDS buffers (two independent QK->transform->PV
// chains per body, 1 barrier per 2 tiles) + in-kernel mask digest (pack_masks
// kernel dropped; raw int32 masks issued body-top, digested post-PV into
// 5 regs/tile: row bit-mask + pre-masked pre-transposed bf16 T fragment).
__global__ __launch_bounds__(256, 2) void alibi_attn(
    const unsigned short* __restrict__ kbp,   // bf16 K [b][k][f]
    const unsigned short* __restrict__ vtp,   // bf16 V^T tiles [b][kt][f][32]
    const float* __restrict__ qp,
    const float* __restrict__ cqp,
    const float* __restrict__ ckp,
    const int* __restrict__ amp,
    const int* __restrict__ almp,
    const float* __restrict__ bsp,
    const float* __restrict__ rmp,
    float* __restrict__ outp)
{
  __shared__ unsigned short kv[4 * BUFS];            // 70 KB, 4-buffer rotation

  const int t    = threadIdx.x;
  const int w    = t >> 6;
  const int lane = t & 63;
  const int l15  = lane & 15;
  const int q4   = lane >> 4;

  const int bid  = blockIdx.x;
  const int xcd  = bid & 7, slot = bid >> 3;
  const int b    = (xcd << 1) | (slot >> 5);
  const int qbase = (slot & 31) * BQ;

  const float bscale = bsp[0] / rmp[0];
  const float sl2 = 0.08838834764831845f * 1.44269504089f;  // scale*log2(e)

  const int kr_st = t >> 3, kc_st = (t & 7) * 16;  // K staging
  const int vf_st = t >> 1, vh_st = (t & 1) * 16;  // V staging
  const int klane0 = 4 * q4;

  const int qrow = qbase + w * 16 + l15;
  const long long mrow = (long long)(b * QL + qrow) * KL;

  const unsigned short* kgb = kbp + (long long)b * KL * FD;
  const unsigned short* vgb = vtp + (long long)b * KL * FD;

  // ---- early VMEM: q-coords + raw masks/coords for tiles 0,1 ----
  float cqx, cqy;
  {
    float2 c2 = *(const float2*)(cqp + ((long long)(b * QL + qrow)) * 2);
    cqx = c2.x; cqy = c2.y;
  }
  i32x4 ram[2][2], ral[2][2];
  f32x4 rck[2][2][2];
  #pragma unroll
  for (int tt = 0; tt < 2; ++tt)
    #pragma unroll
    for (int s = 0; s < 2; ++s) {
      const int kg = tt * BK + s * 16 + klane0;
      ram[tt][s] = __builtin_nontemporal_load((const i32x4*)(amp + mrow + kg));
      ral[tt][s] = __builtin_nontemporal_load((const i32x4*)(almp + mrow + kg));
      rck[tt][s][0] = *(const f32x4*)(ckp + ((long long)(b * KL + kg)) * 2);
      rck[tt][s][1] = *(const f32x4*)(ckp + ((long long)(b * KL + kg)) * 2 + 4);
    }

  // ---- prologue: Q tile -> LDS buf0 (transient), grab B-frags ----
  {
    const float* qg = qp + ((long long)(b * QL + qbase)) * FD;
    #pragma unroll
    for (int i = 0; i < 8; ++i) {
      int idx = t + 256 * i;
      float4 u = ((const float4*)qg)[idx];
      int row = idx >> 5, col = (idx & 31) * 4;
      ushort4 s4; s4.x = f2b(u.x); s4.y = f2b(u.y); s4.z = f2b(u.z); s4.w = f2b(u.w);
      *(ushort4*)&kv[row * KSTR + col] = s4;
    }
  }
  __syncthreads();
  bf16x8 qfrag[4];
  {
    const int m = w * 16 + l15;
    #pragma unroll
    for (int fs = 0; fs < 4; ++fs)
      qfrag[fs] = *(const bf16x8*)&kv[m * KSTR + fs * 32 + q4 * 8];
  }
  __syncthreads();

  // cross-lane gather sources for the P/T transpose
  const int srcA = l15 + ((q4 & 1) << 5);
  const int srcB = srcA + 16;
  const bool lowhalf = (q4 < 2);

  // ---- stage K/V tiles 0,1 into bufs 0,1; digest tiles 0,1 ----
  unsigned dg_amw[2][2];
  u32x4    dg_ta[2][2];
  #pragma unroll
  for (int tt = 0; tt < 2; ++tt) {
    bf16x8 k0l = *(const bf16x8*)(kgb + (tt * BK + kr_st) * FD + kc_st);
    bf16x8 k1l = *(const bf16x8*)(kgb + (tt * BK + kr_st) * FD + kc_st + 8);
    bf16x8 v0l = *(const bf16x8*)(vgb + tt * (BK * FD) + t * 16);
    bf16x8 v1l = *(const bf16x8*)(vgb + tt * (BK * FD) + t * 16 + 8);
    unsigned short* wbuf = kv + tt * BUFS;
    *(bf16x8*)&wbuf[kr_st * KSTR + kc_st]     = k0l;
    *(bf16x8*)&wbuf[kr_st * KSTR + kc_st + 8] = k1l;
    *(bf16x8*)&wbuf[VTOFF + vf_st * VTSTR + vh_st]     = v0l;
    *(bf16x8*)&wbuf[VTOFF + vf_st * VTSTR + vh_st + 8] = v1l;
    digest_tile(ram[tt], ral[tt], rck[tt], cqx, cqy, bscale, klane0,
                srcA, srcB, lowhalf, dg_amw[0][tt], dg_ta[0][tt]);
  }
  __syncthreads();

  f32x4 O1[8], O2[8];
  #pragma unroll
  for (int n = 0; n < 8; ++n) {
    O1[n] = (f32x4){0.f, 0.f, 0.f, 0.f};
    O2[n] = (f32x4){0.f, 0.f, 0.f, 0.f};
  }
  float lsum = 0.f;

  #pragma unroll 2
  for (int i = 0; i < NPAIR; ++i) {
    const int cur = i & 1, nxt = cur ^ 1;
    const unsigned short* rb = kv + (cur ? 2 * BUFS : 0);
    unsigned short*       wb = kv + (nxt ? 2 * BUFS : 0);
    const int tp = (i + 1 < NPAIR) ? (i + 1) : (NPAIR - 1);

    // ---- top: issue K/V regs + raw masks/coords for pair tp ----
    bf16x8 krg[2][2], vrg[2][2];
    #pragma unroll
    for (int tt = 0; tt < 2; ++tt) {
      const int tg = 2 * tp + tt;
      krg[tt][0] = *(const bf16x8*)(kgb + (tg * BK + kr_st) * FD + kc_st);
      krg[tt][1] = *(const bf16x8*)(kgb + (tg * BK + kr_st) * FD + kc_st + 8);
      vrg[tt][0] = *(const bf16x8*)(vgb + tg * (BK * FD) + t * 16);
      vrg[tt][1] = *(const bf16x8*)(vgb + tg * (BK * FD) + t * 16 + 8);
      #pragma unroll
      for (int s = 0; s < 2; ++s) {
        const int kg = tg * BK + s * 16 + klane0;
        ram[tt][s] = __builtin_nontemporal_load((const i32x4*)(amp + mrow + kg));
        ral[tt][s] = __builtin_nontemporal_load((const i32x4*)(almp + mrow + kg));
        rck[tt][s][0] = *(const f32x4*)(ckp + ((long long)(b * KL + kg)) * 2);
        rck[tt][s][1] = *(const f32x4*)(ckp + ((long long)(b * KL + kg)) * 2 + 4);
      }
    }

    // ---- two independent tile chains ----
    #pragma unroll
    for (int tt = 0; tt < 2; ++tt) {
      const unsigned short* buf = rb + tt * BUFS;

      // QK^T (swapped): lane holds S[k = s*16+4*q4+r][q = l15]
      f32x4 S0 = (f32x4){0.f, 0.f, 0.f, 0.f};
      f32x4 S1 = (f32x4){0.f, 0.f, 0.f, 0.f};
      #pragma unroll
      for (int fs = 0; fs < 4; ++fs) {
        bf16x8 kb0 = *(const bf16x8*)&buf[(l15)      * KSTR + fs * 32 + q4 * 8];
        bf16x8 kb1 = *(const bf16x8*)&buf[(16 + l15) * KSTR + fs * 32 + q4 * 8];
        S0 = __builtin_amdgcn_mfma_f32_16x16x32_bf16(kb0, qfrag[fs], S0, 0, 0, 0);
        S1 = __builtin_amdgcn_mfma_f32_16x16x32_bf16(kb1, qfrag[fs], S1, 0, 0, 0);
      }

      // transform: exp2 + bit-test only (T frag pre-digested)
      const unsigned amw = dg_amw[cur][tt];
      float wvv[2][4];
      #pragma unroll
      for (int s = 0; s < 2; ++s) {
        const f32x4 Sv = s ? S1 : S0;
        #pragma unroll
        for (int r = 0; r < 4; ++r) {
          float e = __builtin_amdgcn_exp2f(Sv[r] * sl2);
          lsum += e;
          wvv[s][r] = ((amw >> (s * 16 + klane0 + r)) & 1u) ? 0.f : e;
        }
      }
      unsigned aX0 = cvt_pk_bf16(wvv[0][0], wvv[0][1]);
      unsigned aX1 = cvt_pk_bf16(wvv[0][2], wvv[0][3]);
      unsigned aX2 = cvt_pk_bf16(wvv[1][0], wvv[1][1]);
      unsigned aX3 = cvt_pk_bf16(wvv[1][2], wvv[1][3]);
      u32x4 wa;
      {
        int y0, y2;
        y0 = __shfl((int)aX0, srcA, 64); y2 = __shfl((int)aX2, srcA, 64);
        wa[0] = (unsigned)(lowhalf ? y0 : y2);
        y0 = __shfl((int)aX1, srcA, 64); y2 = __shfl((int)aX3, srcA, 64);
        wa[1] = (unsigned)(lowhalf ? y0 : y2);
        y0 = __shfl((int)aX0, srcB, 64); y2 = __shfl((int)aX2, srcB, 64);
        wa[2] = (unsigned)(lowhalf ? y0 : y2);
        y0 = __shfl((int)aX1, srcB, 64); y2 = __shfl((int)aX3, srcB, 64);
        wa[3] = (unsigned)(lowhalf ? y0 : y2);
      }
      bf16x8 aw = __builtin_bit_cast(bf16x8, wa);
      bf16x8 at = __builtin_bit_cast(bf16x8, dg_ta[cur][tt]);

      // PV
      #pragma unroll
      for (int n = 0; n < 8; ++n) {
        bf16x8 vb = *(const bf16x8*)&buf[VTOFF + (n * 16 + l15) * VTSTR + q4 * 8];
        O1[n] = __builtin_amdgcn_mfma_f32_16x16x32_bf16(aw, vb, O1[n], 0, 0, 0);
        O2[n] = __builtin_amdgcn_mfma_f32_16x16x32_bf16(at, vb, O2[n], 0, 0, 0);
      }

      // digest raw tile tt of pair tp (issued body-top; ~2K cyc of cover)
      digest_tile(ram[tt], ral[tt], rck[tt], cqx, cqy, bscale, klane0,
                  srcA, srcB, lowhalf, dg_amw[nxt][tt], dg_ta[nxt][tt]);
    }

    // ---- drain K/V regs -> the buffers read in body i-1 ----
    #pragma unroll
    for (int tt = 0; tt < 2; ++tt) {
      unsigned short* wbuf = wb + tt * BUFS;
      *(bf16x8*)&wbuf[kr_st * KSTR + kc_st]     = krg[tt][0];
      *(bf16x8*)&wbuf[kr_st * KSTR + kc_st + 8] = krg[tt][1];
      *(bf16x8*)&wbuf[VTOFF + vf_st * VTSTR + vh_st]     = vrg[tt][0];
      *(bf16x8*)&wbuf[VTOFF + vf_st * VTSTR + vh_st + 8] = vrg[tt][1];
    }

    // barrier draining ONLY LDS: in-flight VMEM prefetches survive
    asm volatile("s_waitcnt lgkmcnt(0)\n\ts_barrier" ::: "memory");
  }

  // ---- epilogue: lane-local lsum -> per-row totals, combine, store ----
  lsum += __shfl_xor(lsum, 16, 64);
  lsum += __shfl_xor(lsum, 32, 64);
  float linv[4];
  #pragma unroll
  for (int r = 0; r < 4; ++r) linv[r] = 1.0f / __shfl(lsum, q4 * 4 + r, 64);

  #pragma unroll
  for (int n = 0; n < 8; ++n) {
    #pragma unroll
    for (int r = 0; r < 4; ++r) {
      const int qg_ = qbase + w * 16 + q4 * 4 + r;
      const int f   = n * 16 + l15;
      float val = O1[n][r] * linv[r] - O2[n][r];
      __builtin_nontemporal_store(val, outp + ((long long)(b * QL + qg_)) * FD + f);
    }
  }
}

extern "C" void kernel_launch(void* const* d_in, const int* in_sizes, int n_in,
                              void* d_out, int out_size, void* d_ws, size_t ws_size,
                              hipStream_t stream) {
  const float* q   = (const float*)d_in[0];
  const float* k   = (const float*)d_in[1];
  const float* v   = (const float*)d_in[2];
  const float* cq  = (const float*)d_in[3];
  const float* ck  = (const float*)d_in[4];
  const int*   am  = (const int*)d_in[5];
  const int*   alm = (const int*)d_in[6];
  const float* bs  = (const float*)d_in[7];
  const float* rm  = (const float*)d_in[8];
  float*       out = (float*)d_out;

  unsigned short* kb = (unsigned short*)d_ws;            // 8 MB bf16 K
  unsigned short* vt = kb + WS_HALF;                     // 8 MB bf16 V^T tiles

  hipLaunchKernelGGL(conv_k,  dim3(WS_HALF / 1024), dim3(256), 0, stream, k, kb);
  hipLaunchKernelGGL(conv_vt, dim3(B_ * 64),        dim3(256), 0, stream, v, vt);

  dim3 grid(B_ * (QL / BQ));   // 512 blocks, 2/CU
  dim3 block(256);
  hipLaunchKernelGGL(alibi_attn, grid, block, 0, stream,
                     kb, vt, q, cq, ck, am, alm, bs, rm, out);
}

// Round 7
// 692.241 us; speedup vs baseline: 1.5489x; 1.0249x over previous
//
#include <hip/hip_runtime.h>
#include <stdint.h>

#define B_  16
#define QL  2048
#define KL  2048
#define FD  128
#define BQ  64
#define BK  32
#define NSTEP (KL/BK)

#define KSTR  136        // K-tile LDS row stride (shorts)
#define VTOFF 4352       // 32*136
#define VTSTR 36         // V^T LDS row stride (shorts)
#define BUFS  8960       // 4352 + 128*36 shorts per buffer
#define WS_HALF (B_*KL*FD)   // shorts per converted array (8 MB)

typedef __attribute__((ext_vector_type(8))) short bf16x8;
typedef __attribute__((ext_vector_type(4))) float f32x4;
typedef __attribute__((ext_vector_type(4))) int   i32x4;
typedef __attribute__((ext_vector_type(4))) unsigned int u32x4;

__device__ __forceinline__ unsigned short f2b(float f) {
  union { float f; unsigned u; } x; x.f = f;
  return (unsigned short)((x.u + 0x8000u) >> 16);
}

__device__ __forceinline__ unsigned cvt_pk_bf16(float lo, float hi) {
  unsigned r;
  asm("v_cvt_pk_bf16_f32 %0, %1, %2" : "=v"(r) : "v"(lo), "v"(hi));
  return r;
}

// ---- pre-pass 1: K fp32 -> bf16, same layout ----
__global__ __launch_bounds__(256) void conv_k(const float* __restrict__ kp,
                                              unsigned short* __restrict__ kb) {
  int idx = (blockIdx.x * 256 + threadIdx.x) * 4;
  float4 u = *(const float4*)(kp + idx);
  ushort4 s4; s4.x = f2b(u.x); s4.y = f2b(u.y); s4.z = f2b(u.z); s4.w = f2b(u.w);
  *(ushort4*)(kb + idx) = s4;
}

// ---- pre-pass 2: V fp32 [b][k][f] -> bf16 tiled-transposed [b][kt][f][32] ----
__global__ __launch_bounds__(256) void conv_vt(const float* __restrict__ vp,
                                               unsigned short* __restrict__ vt) {
  __shared__ float tl[32 * 132];
  const int t = threadIdx.x, b = blockIdx.x >> 6, kt = blockIdx.x & 63;
  const int r = t >> 3, f0 = (t & 7) * 16;
  const float* src = vp + ((long long)(b * KL + kt * 32 + r)) * FD + f0;
  #pragma unroll
  for (int i = 0; i < 4; ++i)
    *(float4*)&tl[r * 132 + f0 + 4 * i] = *(const float4*)(src + 4 * i);
  __syncthreads();
  const int f = t >> 1, half = t & 1;
  bf16x8 o0, o1;
  #pragma unroll
  for (int j = 0; j < 8; ++j)  o0[j] = (short)f2b(tl[(half * 16 + j) * 132 + f]);
  #pragma unroll
  for (int j = 0; j < 8; ++j)  o1[j] = (short)f2b(tl[(half * 16 + 8 + j) * 132 + f]);
  unsigned short* dst = vt + ((long long)((b * 64 + kt) * FD + f)) * 32 + half * 16;
  *(bf16x8*)dst = o0;
  *(bf16x8*)(dst + 8) = o1;
}

// out = (sum_k !attn*e^s*V)/l - sum_k !attn*!alibi*d*bscale*V,  l = sum_k e^s
//
// R7: producer/consumer wave specialization. 512-thread block: waves 0-3
// consume (QK MFMA -> exp2+bit-test -> bpermute P -> PV MFMA, nothing else);
// waves 4-7 produce (K/V global->LDS dist-1, coalesced mask stream dist-2,
// bit-pack + relayout, full T A-fragment incl. ck/sqrt/mask -> LDS).
// Producers always reach the lgkm-only barrier early; the per-tile convoy
// collapses to the consumer chain. All consumer math identical to R5.
__global__ __launch_bounds__(512, 2) void alibi_attn(
    const unsigned short* __restrict__ kbp,   // bf16 K [b][k][f]
    const unsigned short* __restrict__ vtp,   // bf16 V^T tiles [b][kt][f][32]
    const float* __restrict__ qp,
    const float* __restrict__ cqp,
    const float* __restrict__ ckp,
    const int* __restrict__ amp,
    const int* __restrict__ almp,
    const float* __restrict__ bsp,
    const float* __restrict__ rmp,
    float* __restrict__ outp)
{
  __shared__ unsigned short kv[2 * BUFS];   // 35 KB K + V^T dbuf
  __shared__ u32x4 t_lds[2][256];           // 8 KB digested T A-frags (dbuf)
  __shared__ unsigned amw_lds[2][64];       // 512 B am row-words (dbuf)

  const int t    = threadIdx.x;
  const int lane = t & 63;
  const int l15  = lane & 15;
  const int q4   = lane >> 4;
  const bool is_prod = (t >= 256);

  const int bid  = blockIdx.x;
  const int xcd  = bid & 7, slot = bid >> 3;
  const int b    = (xcd << 1) | (slot >> 5);
  const int qbase = (slot & 31) * BQ;

  const float sl2 = 0.08838834764831845f * 1.44269504089f;  // scale*log2(e)

  const unsigned short* kgb = kbp + (long long)b * KL * FD;
  const unsigned short* vgb = vtp + (long long)b * KL * FD;

  // ---- producer-side persistent state ----
  const int tp = t & 255;                      // 0..255 within producer half
  const int kr_st = tp >> 3, kc_st = (tp & 7) * 16;   // K staging
  const int vf_st = tp >> 1, vh_st = (tp & 1) * 16;   // V staging
  const int pw = (t >> 6) & 3;                 // producer wave == consumer wave fed
  const int mrow16 = lane >> 2, moct = lane & 3;      // mask-load layout
  const long long mrowP = (long long)(b * QL + qbase + pw * 16 + mrow16) * KL;
  const int qrowT = qbase + pw * 16 + l15;     // row for T-frag layout
  const float bscale = bsp[0] / rmp[0];
  float cqxP = 0.f, cqyP = 0.f;

  i32x4 am0[2], am1[2], al0[2], al1[2];        // mask dbuf (dist-2)
  bf16x8 krg[2], vrg[2];                       // K/V dist-1 regs

  // digest one tile's products into slot `sl` from mask set `sC`
  auto produce = [&](int sC, int sl, int tile) {
    unsigned am8 = 0, ob8 = 0;
    #pragma unroll
    for (int j = 0; j < 4; ++j) {
      am8 |= (am0[sC][j] ? 1u : 0u) << j;
      am8 |= (am1[sC][j] ? 1u : 0u) << (4 + j);
      ob8 |= ((am0[sC][j] | al0[sC][j]) ? 1u : 0u) << j;
      ob8 |= ((am1[sC][j] | al1[sC][j]) ? 1u : 0u) << (4 + j);
    }
    unsigned pk = am8 | (ob8 << 8);
    // am row-word: bit k (0..31) of this row
    unsigned amw = am8 << (moct * 8);
    amw |= (unsigned)__shfl_xor((int)amw, 1, 64);
    amw |= (unsigned)__shfl_xor((int)amw, 2, 64);
    if (moct == 0) amw_lds[sl][pw * 16 + mrow16] = amw;
    // relayout ob bits: target lane (l15,q4) <- source lane 4*l15+q4
    unsigned pkT = (unsigned)__shfl((int)pk, 4 * l15 + q4, 64);
    unsigned obT = (pkT >> 8) & 0xFFu;
    // ck coords for k = tile*32 + 8*q4 + j (broadcast per q4-group, L2)
    const long long cb = ((long long)(b * KL + tile * BK + 8 * q4)) * 2;
    f32x4 cc[4];
    cc[0] = *(const f32x4*)(ckp + cb);
    cc[1] = *(const f32x4*)(ckp + cb + 4);
    cc[2] = *(const f32x4*)(ckp + cb + 8);
    cc[3] = *(const f32x4*)(ckp + cb + 12);
    float tv[8];
    #pragma unroll
    for (int j = 0; j < 8; ++j) {
      float ckx = cc[j >> 1][(j & 1) * 2];
      float cky = cc[j >> 1][(j & 1) * 2 + 1];
      float dx = cqxP - ckx, dy = cqyP - cky;
      float d  = sqrtf(fmaf(dx, dx, dy * dy)) * bscale;
      tv[j] = ((obT >> j) & 1u) ? 0.f : d;
    }
    u32x4 ta;
    ta[0] = cvt_pk_bf16(tv[0], tv[1]);
    ta[1] = cvt_pk_bf16(tv[2], tv[3]);
    ta[2] = cvt_pk_bf16(tv[4], tv[5]);
    ta[3] = cvt_pk_bf16(tv[6], tv[7]);
    t_lds[sl][pw * 64 + lane] = ta;
  };

  // ---- prologue stage 1: consumers stage Q; producers issue tile0 loads ----
  if (!is_prod) {
    const float* qg = qp + ((long long)(b * QL + qbase)) * FD;
    #pragma unroll
    for (int i = 0; i < 8; ++i) {
      int idx = t + 256 * i;
      float4 u = ((const float4*)qg)[idx];
      int row = idx >> 5, col = (idx & 31) * 4;
      ushort4 s4; s4.x = f2b(u.x); s4.y = f2b(u.y); s4.z = f2b(u.z); s4.w = f2b(u.w);
      *(ushort4*)&kv[row * KSTR + col] = s4;
    }
  } else {
    float2 c2 = *(const float2*)(cqp + ((long long)(b * QL + qrowT)) * 2);
    cqxP = c2.x; cqyP = c2.y;
    const int kg = moct * 8;
    am0[0] = __builtin_nontemporal_load((const i32x4*)(amp + mrowP + kg));
    am1[0] = __builtin_nontemporal_load((const i32x4*)(amp + mrowP + kg + 4));
    al0[0] = __builtin_nontemporal_load((const i32x4*)(almp + mrowP + kg));
    al1[0] = __builtin_nontemporal_load((const i32x4*)(almp + mrowP + kg + 4));
    krg[0] = *(const bf16x8*)(kgb + kr_st * FD + kc_st);
    krg[1] = *(const bf16x8*)(kgb + kr_st * FD + kc_st + 8);
    vrg[0] = *(const bf16x8*)(vgb + tp * 16);
    vrg[1] = *(const bf16x8*)(vgb + tp * 16 + 8);
  }
  __syncthreads();

  // ---- stage 2: consumers read Q frags; producers digest tile0, issue tile1 masks ----
  bf16x8 qfrag[4];
  if (!is_prod) {
    const int m = (t >> 6) * 16 + l15;
    #pragma unroll
    for (int fs = 0; fs < 4; ++fs)
      qfrag[fs] = *(const bf16x8*)&kv[m * KSTR + fs * 32 + q4 * 8];
  } else {
    produce(0, 0, 0);
    const int kg = BK + moct * 8;
    am0[1] = __builtin_nontemporal_load((const i32x4*)(amp + mrowP + kg));
    am1[1] = __builtin_nontemporal_load((const i32x4*)(amp + mrowP + kg + 4));
    al0[1] = __builtin_nontemporal_load((const i32x4*)(almp + mrowP + kg));
    al1[1] = __builtin_nontemporal_load((const i32x4*)(almp + mrowP + kg + 4));
  }
  __syncthreads();

  // ---- stage 3: producers write K/V tile0 into buf0 ----
  if (is_prod) {
    *(bf16x8*)&kv[kr_st * KSTR + kc_st]     = krg[0];
    *(bf16x8*)&kv[kr_st * KSTR + kc_st + 8] = krg[1];
    *(bf16x8*)&kv[VTOFF + vf_st * VTSTR + vh_st]     = vrg[0];
    *(bf16x8*)&kv[VTOFF + vf_st * VTSTR + vh_st + 8] = vrg[1];
  }
  __syncthreads();

  f32x4 O1[8], O2[8];
  #pragma unroll
  for (int n = 0; n < 8; ++n) {
    O1[n] = (f32x4){0.f, 0.f, 0.f, 0.f};
    O2[n] = (f32x4){0.f, 0.f, 0.f, 0.f};
  }
  float lsum = 0.f;

  const int srcA = l15 + ((q4 & 1) << 5);
  const int srcB = srcA + 16;
  const bool lowhalf = (q4 < 2);

  #pragma unroll 2
  for (int i = 0; i < NSTEP; ++i) {
    const int cur = i & 1, nxt = cur ^ 1;
    if (!is_prod) {
      const unsigned short* buf = kv + cur * BUFS;
      // QK^T (swapped): lane holds S[k = s*16+4*q4+r][q = l15]
      f32x4 S0 = (f32x4){0.f, 0.f, 0.f, 0.f};
      f32x4 S1 = (f32x4){0.f, 0.f, 0.f, 0.f};
      #pragma unroll
      for (int fs = 0; fs < 4; ++fs) {
        bf16x8 kb0 = *(const bf16x8*)&buf[(l15)      * KSTR + fs * 32 + q4 * 8];
        bf16x8 kb1 = *(const bf16x8*)&buf[(16 + l15) * KSTR + fs * 32 + q4 * 8];
        S0 = __builtin_amdgcn_mfma_f32_16x16x32_bf16(kb0, qfrag[fs], S0, 0, 0, 0);
        S1 = __builtin_amdgcn_mfma_f32_16x16x32_bf16(kb1, qfrag[fs], S1, 0, 0, 0);
      }
      // transform: exp2 + bit-test (mask word from LDS broadcast)
      const unsigned amw = amw_lds[cur][(t >> 6) * 16 + l15];
      float wvv[2][4];
      #pragma unroll
      for (int s = 0; s < 2; ++s) {
        const f32x4 Sv = s ? S1 : S0;
        #pragma unroll
        for (int r = 0; r < 4; ++r) {
          float e = __builtin_amdgcn_exp2f(Sv[r] * sl2);
          lsum += e;
          wvv[s][r] = ((amw >> (s * 16 + 4 * q4 + r)) & 1u) ? 0.f : e;
        }
      }
      unsigned aX0 = cvt_pk_bf16(wvv[0][0], wvv[0][1]);
      unsigned aX1 = cvt_pk_bf16(wvv[0][2], wvv[0][3]);
      unsigned aX2 = cvt_pk_bf16(wvv[1][0], wvv[1][1]);
      unsigned aX3 = cvt_pk_bf16(wvv[1][2], wvv[1][3]);
      u32x4 wa;
      {
        int y0, y2;
        y0 = __shfl((int)aX0, srcA, 64); y2 = __shfl((int)aX2, srcA, 64);
        wa[0] = (unsigned)(lowhalf ? y0 : y2);
        y0 = __shfl((int)aX1, srcA, 64); y2 = __shfl((int)aX3, srcA, 64);
        wa[1] = (unsigned)(lowhalf ? y0 : y2);
        y0 = __shfl((int)aX0, srcB, 64); y2 = __shfl((int)aX2, srcB, 64);
        wa[2] = (unsigned)(lowhalf ? y0 : y2);
        y0 = __shfl((int)aX1, srcB, 64); y2 = __shfl((int)aX3, srcB, 64);
        wa[3] = (unsigned)(lowhalf ? y0 : y2);
      }
      bf16x8 aw = __builtin_bit_cast(bf16x8, wa);
      bf16x8 at = __builtin_bit_cast(bf16x8, t_lds[cur][(t >> 6) * 64 + lane]);
      // PV
      #pragma unroll
      for (int n = 0; n < 8; ++n) {
        bf16x8 vb = *(const bf16x8*)&buf[VTOFF + (n * 16 + l15) * VTSTR + q4 * 8];
        O1[n] = __builtin_amdgcn_mfma_f32_16x16x32_bf16(aw, vb, O1[n], 0, 0, 0);
        O2[n] = __builtin_amdgcn_mfma_f32_16x16x32_bf16(at, vb, O2[n], 0, 0, 0);
      }
    } else {
      const int tn = (i + 1 < NSTEP) ? (i + 1) : (NSTEP - 1);  // K/V + digest tile
      const int tf = (i + 2 < NSTEP) ? (i + 2) : (NSTEP - 1);  // mask issue tile
      // issue K/V tile tn (dist-1, drained below)
      krg[0] = *(const bf16x8*)(kgb + (tn * BK + kr_st) * FD + kc_st);
      krg[1] = *(const bf16x8*)(kgb + (tn * BK + kr_st) * FD + kc_st + 8);
      vrg[0] = *(const bf16x8*)(vgb + tn * (BK * FD) + tp * 16);
      vrg[1] = *(const bf16x8*)(vgb + tn * (BK * FD) + tp * 16 + 8);
      // issue masks tile tf -> set cur (dist-2, coalesced row-major)
      const int kg = tf * BK + moct * 8;
      am0[cur] = __builtin_nontemporal_load((const i32x4*)(amp + mrowP + kg));
      am1[cur] = __builtin_nontemporal_load((const i32x4*)(amp + mrowP + kg + 4));
      al0[cur] = __builtin_nontemporal_load((const i32x4*)(almp + mrowP + kg));
      al1[cur] = __builtin_nontemporal_load((const i32x4*)(almp + mrowP + kg + 4));
      // digest tile tn from set nxt -> slots nxt
      produce(nxt, nxt, tn);
      // drain K/V regs -> buf nxt
      unsigned short* nb = kv + nxt * BUFS;
      *(bf16x8*)&nb[kr_st * KSTR + kc_st]     = krg[0];
      *(bf16x8*)&nb[kr_st * KSTR + kc_st + 8] = krg[1];
      *(bf16x8*)&nb[VTOFF + vf_st * VTSTR + vh_st]     = vrg[0];
      *(bf16x8*)&nb[VTOFF + vf_st * VTSTR + vh_st + 8] = vrg[1];
    }
    // barrier draining ONLY LDS: in-flight VMEM prefetches survive
    asm volatile("s_waitcnt lgkmcnt(0)\n\ts_barrier" ::: "memory");
  }

  // ---- epilogue (consumers only) ----
  if (!is_prod) {
    lsum += __shfl_xor(lsum, 16, 64);
    lsum += __shfl_xor(lsum, 32, 64);
    float linv[4];
    #pragma unroll
    for (int r = 0; r < 4; ++r) linv[r] = 1.0f / __shfl(lsum, q4 * 4 + r, 64);
    const int w = t >> 6;
    #pragma unroll
    for (int n = 0; n < 8; ++n) {
      #pragma unroll
      for (int r = 0; r < 4; ++r) {
        const int qg_ = qbase + w * 16 + q4 * 4 + r;
        const int f   = n * 16 + l15;
        float val = O1[n][r] * linv[r] - O2[n][r];
        __builtin_nontemporal_store(val, outp + ((long long)(b * QL + qg_)) * FD + f);
      }
    }
  }
}

extern "C" void kernel_launch(void* const* d_in, const int* in_sizes, int n_in,
                              void* d_out, int out_size, void* d_ws, size_t ws_size,
                              hipStream_t stream) {
  const float* q   = (const float*)d_in[0];
  const float* k   = (const float*)d_in[1];
  const float* v   = (const float*)d_in[2];
  const float* cq  = (const float*)d_in[3];
  const float* ck  = (const float*)d_in[4];
  const int*   am  = (const int*)d_in[5];
  const int*   alm = (const int*)d_in[6];
  const float* bs  = (const float*)d_in[7];
  const float* rm  = (const float*)d_in[8];
  float*       out = (float*)d_out;

  unsigned short* kb = (unsigned short*)d_ws;            // 8 MB bf16 K
  unsigned short* vt = kb + WS_HALF;                     // 8 MB bf16 V^T tiles

  hipLaunchKernelGGL(conv_k,  dim3(WS_HALF / 1024), dim3(256), 0, stream, k, kb);
  hipLaunchKernelGGL(conv_vt, dim3(B_ * 64),        dim3(256), 0, stream, v, vt);

  dim3 grid(B_ * (QL / BQ));   // 512 blocks
  dim3 block(512);             // 4 consumer + 4 producer waves
  hipLaunchKernelGGL(alibi_attn, grid, block, 0, stream,
                     kb, vt, q, cq, ck, am, alm, bs, rm, out);
}